// Round 6
// baseline (476.464 us; speedup 1.0000x reference)
//
#include <hip/hip_runtime.h>
#include <hip/hip_bf16.h>

typedef unsigned int uint32;
typedef unsigned short ushort16;

using bf16x8 = __attribute__((ext_vector_type(8))) short;
using f32x4  = __attribute__((ext_vector_type(4))) float;

#define N_MATN 100000
#define N_ELEMN 118
#define F_MATN 128
#define F_ELEMN 64
#define HIDN 128
#define NHEAD 8
#define OUTC 64
#define NSTRIPS 6250              // 100000 / 16
#define NT2 16
#define NTILES2 (N_MATN/NT2)

// bucketed scatter params
#define SH 8                      // 256 dst nodes per bucket
#define NBK 391                   // ceil(100000/256)
#define BCH 8192                  // edges per bin chunk (368 chunks > 256 CUs)

__device__ __forceinline__ float blo(uint32 u){ return __uint_as_float(u << 16); }
__device__ __forceinline__ float bhi(uint32 u){ return __uint_as_float(u & 0xffff0000u); }
__device__ __forceinline__ ushort16 f2bf(float f){
    uint32 u = __float_as_uint(f);
    uint32 r = u + 0x7FFFu + ((u >> 16) & 1u);   // RNE
    return (ushort16)(r >> 16);
}
__device__ __forceinline__ uint32 pack2(float a, float b){
    return (uint32)f2bf(a) | ((uint32)f2bf(b) << 16);
}
__device__ __forceinline__ bf16x8 cvt8(const float* __restrict__ p){
    bf16x8 r;
    #pragma unroll
    for(int j=0;j<8;j++) r[j] = (short)f2bf(p[j]);
    return r;
}

// ---------------- fused projection: blocks [0,118) elem, rest mat-MFMA
__global__ __launch_bounds__(256) void proj_all(
    const float* __restrict__ xe, const float* __restrict__ We,
    const float* __restrict__ be, const float* __restrict__ a_se,
    ushort16* __restrict__ h_elem, float* __restrict__ asrc_em,
    const float* __restrict__ x, const float* __restrict__ W,
    const float* __restrict__ bias,
    const float* __restrict__ a_de, const float* __restrict__ a_sm, const float* __restrict__ a_dm,
    ushort16* __restrict__ h,
    float* __restrict__ adst_em, float* __restrict__ asrc_mm, float* __restrict__ adst_mm)
{
    __shared__ float xr[F_ELEMN];
    int tid = threadIdx.x;
    if(blockIdx.x < N_ELEMN){
        // ---- elem projection (one block per node, 128 active threads)
        int n = blockIdx.x, c = tid;
        if(c < 16) ((float4*)xr)[c] = ((const float4*)(xe + n*F_ELEMN))[c];
        __syncthreads();
        if(c < 128){
            const float4* Wr = (const float4*)(We + c*F_ELEMN);
            float acc = 0.f;
            #pragma unroll 4
            for(int i=0;i<16;i++){
                float4 w = Wr[i];
                acc += xr[4*i]*w.x + xr[4*i+1]*w.y + xr[4*i+2]*w.z + xr[4*i+3]*w.w;
            }
            acc += be[c];
            h_elem[n*HIDN + c] = f2bf(acc);
            float p = acc * a_se[c];
            #pragma unroll
            for(int m=8;m>=1;m>>=1) p += __shfl_xor(p, m, 16);
            if((c&15)==0) asrc_em[n*NHEAD + (c>>4)] = p;
        }
        return;
    }
    // ---- mat projection (MFMA 16x16x32 bf16)
    int wv = tid >> 6, lane = tid & 63, quad = lane >> 4, sl = lane & 15;
    bf16x8 B[2][4];
    float bc[2], ade[2], asv[2], adv[2];
    #pragma unroll
    for(int i=0;i<2;i++){
        int c = (2*wv+i)*16 + sl;
        const float* wr = W + c*F_MATN;
        #pragma unroll
        for(int ks=0;ks<4;ks++) B[i][ks] = cvt8(wr + ks*32 + quad*8);
        bc[i] = bias[c]; ade[i] = a_de[c]; asv[i] = a_sm[c]; adv[i] = a_dm[c];
    }
    int nb = gridDim.x - N_ELEMN;
    for(int s = blockIdx.x - N_ELEMN; s < NSTRIPS; s += nb){
        int n0 = s*16;
        const float* xrow = x + (size_t)(n0+sl)*F_MATN;
        bf16x8 A[4];
        #pragma unroll
        for(int ks=0;ks<4;ks++) A[ks] = cvt8(xrow + ks*32 + quad*8);
        f32x4 acc[2];
        #pragma unroll
        for(int i=0;i<2;i++){ acc[i][0]=0.f; acc[i][1]=0.f; acc[i][2]=0.f; acc[i][3]=0.f; }
        #pragma unroll
        for(int i=0;i<2;i++)
            #pragma unroll
            for(int ks=0;ks<4;ks++)
                acc[i] = __builtin_amdgcn_mfma_f32_16x16x32_bf16(A[ks], B[i][ks], acc[i], 0, 0, 0);
        #pragma unroll
        for(int i=0;i<2;i++){
            int head = 2*wv + i;
            #pragma unroll
            for(int r=0;r<4;r++){
                float a = acc[i][r] + bc[i];
                int node = n0 + quad*4 + r;
                h[(size_t)node*HIDN + head*16 + sl] = f2bf(a);
                float p0 = a*ade[i], p1 = a*asv[i], p2 = a*adv[i];
                #pragma unroll
                for(int m=8;m>=1;m>>=1){
                    p0 += __shfl_xor(p0, m);
                    p1 += __shfl_xor(p1, m);
                    p2 += __shfl_xor(p2, m);
                }
                if(sl == 0){
                    adst_em[node*NHEAD + head] = p0;
                    asrc_mm[node*NHEAD + head] = p1;
                    adst_mm[node*NHEAD + head] = p2;
                }
            }
        }
    }
}

// ---------------- CSR build stage 1: bucket-level histograms (int4 streaming)
__global__ __launch_bounds__(256) void bucket_count(
    const int* __restrict__ dst_em, int nE_em, int* __restrict__ bcnt_em,
    const int* __restrict__ dst_mm, int nE_mm, int* __restrict__ bcnt_mm)
{
    __shared__ int he[NBK], hm[NBK];
    int t = threadIdx.x;
    for(int i=t;i<NBK;i+=256){ he[i]=0; hm[i]=0; }
    __syncthreads();
    int gt = blockIdx.x*256 + t;
    int st = gridDim.x*256;
    {
        int n4 = nE_em >> 2;
        const int4* d4 = (const int4*)dst_em;
        for(int i = gt; i < n4; i += st){
            int4 v = d4[i];
            atomicAdd(&he[v.x>>SH],1); atomicAdd(&he[v.y>>SH],1);
            atomicAdd(&he[v.z>>SH],1); atomicAdd(&he[v.w>>SH],1);
        }
        for(int i = (n4<<2) + gt; i < nE_em; i += st) atomicAdd(&he[dst_em[i]>>SH],1);
    }
    {
        int n4 = nE_mm >> 2;
        const int4* d4 = (const int4*)dst_mm;
        for(int i = gt; i < n4; i += st){
            int4 v = d4[i];
            atomicAdd(&hm[v.x>>SH],1); atomicAdd(&hm[v.y>>SH],1);
            atomicAdd(&hm[v.z>>SH],1); atomicAdd(&hm[v.w>>SH],1);
        }
        for(int i = (n4<<2) + gt; i < nE_mm; i += st) atomicAdd(&hm[dst_mm[i]>>SH],1);
    }
    __syncthreads();
    for(int j=t;j<NBK;j+=256){
        int a = he[j], b = hm[j];
        if(a) atomicAdd(&bcnt_em[j], a);
        if(b) atomicAdd(&bcnt_mm[j], b);
    }
}

// ---------------- CSR build stage 2: scan 391 bucket counts (both types), 1 block
__global__ __launch_bounds__(512) void bucket_scan(
    const int* __restrict__ bcnt_em, int* __restrict__ bb_em, int* __restrict__ bcur_em,
    const int* __restrict__ bcnt_mm, int* __restrict__ bb_mm, int* __restrict__ bcur_mm,
    int* __restrict__ offs_em, int* __restrict__ offs_mm, int nE_em, int nE_mm)
{
    __shared__ int wsum[8];
    int t = threadIdx.x, l = t & 63, w = t >> 6;
    // ---- em
    {
        int v = (t < NBK) ? bcnt_em[t] : 0;
        int x = v;
        #pragma unroll
        for(int off=1; off<64; off<<=1){ int y = __shfl_up(x, off); if(l >= off) x += y; }
        if(l == 63) wsum[w] = x;
        __syncthreads();
        int base = 0;
        for(int k=0;k<w;k++) base += wsum[k];
        int excl = base + x - v;
        if(t < NBK){ bb_em[t] = excl; bcur_em[t] = excl; }
        if(t == 0){ bb_em[NBK] = nE_em; offs_em[N_MATN] = nE_em; }
        __syncthreads();
    }
    // ---- mm
    {
        int v = (t < NBK) ? bcnt_mm[t] : 0;
        int x = v;
        #pragma unroll
        for(int off=1; off<64; off<<=1){ int y = __shfl_up(x, off); if(l >= off) x += y; }
        if(l == 63) wsum[w] = x;
        __syncthreads();
        int base = 0;
        for(int k=0;k<w;k++) base += wsum[k];
        int excl = base + x - v;
        if(t < NBK){ bb_mm[t] = excl; bcur_mm[t] = excl; }
        if(t == 0){ bb_mm[NBK] = nE_mm; offs_mm[N_MATN] = nE_mm; }
    }
}

// ---------------- pass A: bin edges into dst-buckets (dense reserved runs, int4 streams)
// staged entry = (dstLow << 17) | src   (src < 2^17, dstLow < 256)
__global__ __launch_bounds__(256) void bin_pass(
    const int* __restrict__ src_em, const int* __restrict__ dst_em, int nE_em,
    int* __restrict__ bcur_em, uint32* __restrict__ st_em,
    const int* __restrict__ src_mm, const int* __restrict__ dst_mm, int nE_mm,
    int* __restrict__ bcur_mm, uint32* __restrict__ st_mm)
{
    __shared__ int cnt[NBK];
    __shared__ int base[NBK];
    int t = threadIdx.x;
    int nch_em = (nE_em + BCH - 1)/BCH;
    int nch_mm = (nE_mm + BCH - 1)/BCH;
    int ntot = nch_em + nch_mm;
    for(int c = blockIdx.x; c < ntot; c += gridDim.x){
        bool em = c < nch_em;
        const int* src = em ? src_em : src_mm;
        const int* dst = em ? dst_em : dst_mm;
        int nE   = em ? nE_em : nE_mm;
        int* bcur = em ? bcur_em : bcur_mm;
        uint32* st = em ? st_em : st_mm;
        int cc = em ? c : c - nch_em;
        int s = cc*BCH;
        int e = s + BCH; if(e > nE) e = nE;
        int len = e - s;
        int n4 = len >> 2;
        const int4* d4 = (const int4*)(dst + s);
        const int4* s4 = (const int4*)(src + s);
        for(int i=t;i<NBK;i+=256) cnt[i] = 0;
        __syncthreads();
        for(int i=t;i<n4;i+=256){
            int4 v = d4[i];
            atomicAdd(&cnt[v.x>>SH],1); atomicAdd(&cnt[v.y>>SH],1);
            atomicAdd(&cnt[v.z>>SH],1); atomicAdd(&cnt[v.w>>SH],1);
        }
        for(int i = s + (n4<<2) + t; i < e; i += 256) atomicAdd(&cnt[dst[i]>>SH], 1);
        __syncthreads();
        for(int i=t;i<NBK;i+=256){
            int v = cnt[i];
            base[i] = v ? atomicAdd(&bcur[i], v) : 0;
            cnt[i] = 0;
        }
        __syncthreads();
        for(int i=t;i<n4;i+=256){
            int4 dv = d4[i];
            int4 sv = s4[i];
            int b, p;
            b = dv.x>>SH; p = base[b] + atomicAdd(&cnt[b],1);
            st[p] = ((uint32)(dv.x & ((1<<SH)-1)) << 17) | (uint32)sv.x;
            b = dv.y>>SH; p = base[b] + atomicAdd(&cnt[b],1);
            st[p] = ((uint32)(dv.y & ((1<<SH)-1)) << 17) | (uint32)sv.y;
            b = dv.z>>SH; p = base[b] + atomicAdd(&cnt[b],1);
            st[p] = ((uint32)(dv.z & ((1<<SH)-1)) << 17) | (uint32)sv.z;
            b = dv.w>>SH; p = base[b] + atomicAdd(&cnt[b],1);
            st[p] = ((uint32)(dv.w & ((1<<SH)-1)) << 17) | (uint32)sv.w;
        }
        for(int i = s + (n4<<2) + t; i < e; i += 256){
            int d = dst[i];
            int b = d >> SH;
            int p = base[b] + atomicAdd(&cnt[b], 1);
            st[p] = ((uint32)(d & ((1<<SH)-1)) << 17) | (uint32)src[i];
        }
        __syncthreads();
    }
}

// ---------------- pass B: per bucket — derive per-dst offsets (writes offs[]) and place
__global__ __launch_bounds__(256) void place_pass(
    const int* __restrict__ bb_em, const uint32* __restrict__ st_em,
    int* __restrict__ csr_em, int* __restrict__ offs_em,
    const int* __restrict__ bb_mm, const uint32* __restrict__ st_mm,
    int* __restrict__ csr_mm, int* __restrict__ offs_mm)
{
    __shared__ int cnt[256];
    __shared__ int wsum[4];
    __shared__ int cur[256];
    int b = blockIdx.x;
    bool em = b < NBK;
    const int* bb        = em ? bb_em : bb_mm;
    const uint32* stp    = em ? st_em : st_mm;
    int* csr             = em ? csr_em : csr_mm;
    int* offs            = em ? offs_em : offs_mm;
    int bk = em ? b : b - NBK;
    int d0 = bk << SH;
    int t = threadIdx.x, l = t & 63, w = t >> 6;
    int nd = N_MATN - d0; if(nd > 256) nd = 256;
    int beg = bb[bk], end = bb[bk+1];
    cnt[t] = 0;
    __syncthreads();
    for(int i = beg + t; i < end; i += 256)
        atomicAdd(&cnt[stp[i] >> 17], 1);
    __syncthreads();
    int v = cnt[t];
    int x = v;
    #pragma unroll
    for(int off=1; off<64; off<<=1){ int y = __shfl_up(x, off); if(l >= off) x += y; }
    if(l == 63) wsum[w] = x;
    __syncthreads();
    int base = beg;
    for(int k=0;k<w;k++) base += wsum[k];
    int excl = base + x - v;
    cur[t] = excl;
    if(t < nd) offs[d0 + t] = excl;
    __syncthreads();
    for(int i = beg + t; i < end; i += 256){
        uint32 vv = stp[i];
        int dl = (int)(vv >> 17);
        int p = atomicAdd(&cur[dl], 1);
        csr[p] = (int)(vv & 0x1FFFFu);
    }
}

// ---------------- aggregation: 16 lanes/edge, 8 edges/wave-iter, node-meta prefetch
__global__ __launch_bounds__(256) void agg_both(
    const int* __restrict__ offs_em, const int* __restrict__ csr_em,
    const ushort16* __restrict__ h_elem, const float* __restrict__ asrc_em,
    const float* __restrict__ adst_em, ushort16* __restrict__ o_em,
    const int* __restrict__ offs_mm, const int* __restrict__ csr_mm,
    const ushort16* __restrict__ h_mat, const float* __restrict__ asrc_mm,
    const float* __restrict__ adst_mm, ushort16* __restrict__ o_mm)
{
    int lane = threadIdx.x & 63;
    int g = lane >> 4;            // edge slot 0..3
    int q = lane & 15;            // channel quad: channels [q*8, q*8+8)
    int hd = q >> 1;              // head for these channels
    int w = (blockIdx.x*blockDim.x + threadIdx.x) >> 6;
    int nw = (gridDim.x*blockDim.x) >> 6;

    // prefetch first node's metadata
    int begN = 0, endN = 0; float adN = 0.f;
    if(w < 2*N_MATN){
        int nid0 = __builtin_amdgcn_readfirstlane(w);
        bool em0 = nid0 < N_MATN;
        int dx = em0 ? nid0 : nid0 - N_MATN;
        const int* offsx = em0 ? offs_em : offs_mm;
        const float* adpx = em0 ? adst_em : adst_mm;
        begN = offsx[dx]; endN = offsx[dx+1];
        adN = adpx[(unsigned)(dx*NHEAD + hd)];
    }

    for(int nid = w; nid < 2*N_MATN; nid += nw){
        int nidu = __builtin_amdgcn_readfirstlane(nid);
        bool em = nidu < N_MATN;
        int d = em ? nidu : nidu - N_MATN;
        const int*    csr  = em ? csr_em  : csr_mm;
        const uint32* hs   = (const uint32*)(em ? h_elem : h_mat);
        const float*  asp  = em ? asrc_em : asrc_mm;
        uint32*       op   = (uint32*)(em ? o_em : o_mm);
        int beg = begN, end = endN;
        float ad = adN;
        // prefetch NEXT node's metadata; loads complete while the gather loop runs
        int nxt = nidu + nw;
        if(nxt < 2*N_MATN){
            bool emx = nxt < N_MATN;
            int dx = emx ? nxt : nxt - N_MATN;
            const int* offsx = emx ? offs_em : offs_mm;
            const float* adpx = emx ? adst_em : adst_mm;
            begN = offsx[dx]; endN = offsx[dx+1];
            adN = adpx[(unsigned)(dx*NHEAD + hd)];
        }
        float denA = 0.f, denB = 0.f;
        float nloA[4] = {0.f,0.f,0.f,0.f}, nhiA[4] = {0.f,0.f,0.f,0.f};
        float nloB[4] = {0.f,0.f,0.f,0.f}, nhiB[4] = {0.f,0.f,0.f,0.f};
        for(int j0 = beg; j0 < end; j0 += 8){
            int e0 = j0 + 2*g, e1 = e0 + 1;   // adjacent pair -> csr L1 line reuse
            bool v0 = e0 < end, v1 = e1 < end;
            int s0 = csr[(unsigned)(v0 ? e0 : end - 1)];
            int s1 = csr[(unsigned)(v1 ? e1 : end - 1)];
            // issue all four gathers before any dependent math
            float a0 = asp[(unsigned)(s0*NHEAD + hd)];
            float a1 = asp[(unsigned)(s1*NHEAD + hd)];
            const uint4 h0 = *(const uint4*)(hs + (unsigned)(s0*64 + q*4));
            const uint4 h1 = *(const uint4*)(hs + (unsigned)(s1*64 + q*4));
            float al0 = a0 + ad; al0 = fmaxf(al0, 0.2f*al0);
            float ex0 = __expf(al0); ex0 = v0 ? ex0 : 0.f;
            float al1 = a1 + ad; al1 = fmaxf(al1, 0.2f*al1);
            float ex1 = __expf(al1); ex1 = v1 ? ex1 : 0.f;
            denA += ex0; denB += ex1;
            nloA[0] += blo(h0.x)*ex0; nhiA[0] += bhi(h0.x)*ex0;
            nloA[1] += blo(h0.y)*ex0; nhiA[1] += bhi(h0.y)*ex0;
            nloA[2] += blo(h0.z)*ex0; nhiA[2] += bhi(h0.z)*ex0;
            nloA[3] += blo(h0.w)*ex0; nhiA[3] += bhi(h0.w)*ex0;
            nloB[0] += blo(h1.x)*ex1; nhiB[0] += bhi(h1.x)*ex1;
            nloB[1] += blo(h1.y)*ex1; nhiB[1] += bhi(h1.y)*ex1;
            nloB[2] += blo(h1.z)*ex1; nhiB[2] += bhi(h1.z)*ex1;
            nloB[3] += blo(h1.w)*ex1; nhiB[3] += bhi(h1.w)*ex1;
        }
        float den = denA + denB;
        den += __shfl_xor(den, 16); den += __shfl_xor(den, 32);
        float nlo[4], nhi[4];
        #pragma unroll
        for(int k=0;k<4;k++){
            nlo[k] = nloA[k] + nloB[k];
            nhi[k] = nhiA[k] + nhiB[k];
            nlo[k] += __shfl_xor(nlo[k], 16); nlo[k] += __shfl_xor(nlo[k], 32);
            nhi[k] += __shfl_xor(nhi[k], 16); nhi[k] += __shfl_xor(nhi[k], 32);
        }
        if(g == 0){
            float rdn = 1.0f/(den + 1e-16f);
            uint4 pk;
            pk.x = pack2(fmaxf(nlo[0]*rdn, 0.f), fmaxf(nhi[0]*rdn, 0.f));
            pk.y = pack2(fmaxf(nlo[1]*rdn, 0.f), fmaxf(nhi[1]*rdn, 0.f));
            pk.z = pack2(fmaxf(nlo[2]*rdn, 0.f), fmaxf(nhi[2]*rdn, 0.f));
            pk.w = pack2(fmaxf(nlo[3]*rdn, 0.f), fmaxf(nhi[3]*rdn, 0.f));
            *(uint4*)(op + (size_t)d*64 + q*4) = pk;
        }
    }
}

// ---------------- semantic scores — MFMA; block partials atomically into scores[]
__global__ __launch_bounds__(256) void score_mfma(
    const ushort16* __restrict__ o_em, const ushort16* __restrict__ o_mm,
    const float* __restrict__ Wk, const float* __restrict__ bkv,
    const float* __restrict__ qv, float* __restrict__ scores)
{
    int tid = threadIdx.x;
    int wv = tid >> 6, lane = tid & 63, quad = lane >> 4, sl = lane & 15;
    bf16x8 B[2][4];
    float bkc[2], qc[2];
    #pragma unroll
    for(int i=0;i<2;i++){
        int c = (2*wv+i)*16 + sl;
        const float* wr = Wk + c*HIDN;
        #pragma unroll
        for(int ks=0;ks<4;ks++) B[i][ks] = cvt8(wr + ks*32 + quad*8);
        bkc[i] = bkv[c]; qc[i] = qv[c];
    }
    float se = 0.f, sm = 0.f;
    for(int s = blockIdx.x; s < NSTRIPS; s += gridDim.x){
        int n0 = s*16;
        const bf16x8* rowE = (const bf16x8*)(o_em + (size_t)(n0+sl)*HIDN);
        const bf16x8* rowM = (const bf16x8*)(o_mm + (size_t)(n0+sl)*HIDN);
        bf16x8 AE[4], AM[4];
        #pragma unroll
        for(int ks=0;ks<4;ks++){
            AE[ks] = rowE[ks*4 + quad];
            AM[ks] = rowM[ks*4 + quad];
        }
        f32x4 aE[2], aM[2];
        #pragma unroll
        for(int i=0;i<2;i++){
            aE[i][0]=0.f;aE[i][1]=0.f;aE[i][2]=0.f;aE[i][3]=0.f;
            aM[i][0]=0.f;aM[i][1]=0.f;aM[i][2]=0.f;aM[i][3]=0.f;
        }
        #pragma unroll
        for(int i=0;i<2;i++)
            #pragma unroll
            for(int ks=0;ks<4;ks++){
                aE[i] = __builtin_amdgcn_mfma_f32_16x16x32_bf16(AE[ks], B[i][ks], aE[i], 0, 0, 0);
                aM[i] = __builtin_amdgcn_mfma_f32_16x16x32_bf16(AM[ks], B[i][ks], aM[i], 0, 0, 0);
            }
        #pragma unroll
        for(int i=0;i<2;i++)
            #pragma unroll
            for(int r=0;r<4;r++){
                se += qc[i]*tanhf(aE[i][r] + bkc[i]);
                sm += qc[i]*tanhf(aM[i][r] + bkc[i]);
            }
    }
    #pragma unroll
    for(int m=32;m>=1;m>>=1){ se += __shfl_xor(se,m); sm += __shfl_xor(sm,m); }
    __shared__ float red[8];
    if(lane==0){ red[wv*2]=se; red[wv*2+1]=sm; }
    __syncthreads();
    if(tid==0){
        atomicAdd(&scores[0], red[0]+red[2]+red[4]+red[6]);
        atomicAdd(&scores[1], red[1]+red[3]+red[5]+red[7]);
    }
}

// ---------------- final — LDS-tiled, 4 waves/block, 16 nodes/tile
__global__ __launch_bounds__(256) void final_v4(
    const ushort16* __restrict__ o_em, const ushort16* __restrict__ o_mm,
    const float* __restrict__ Wl, const float* __restrict__ blv,
    const float* __restrict__ scores, float* __restrict__ out)
{
    __shared__ float wlds[64*129];
    __shared__ float zlds[NT2*128];
    int t = threadIdx.x;
    for(int i=t;i<2048;i+=256){
        float4 v = ((const float4*)Wl)[i];
        int r = i >> 5, k4 = i & 31;
        float* d = wlds + r*129 + k4*4;
        d[0]=v.x; d[1]=v.y; d[2]=v.z; d[3]=v.w;
    }
    float s0 = scores[0]*(1.0f/N_MATN), s1 = scores[1]*(1.0f/N_MATN);
    float mx = fmaxf(s0,s1);
    float e0 = __expf(s0-mx), e1 = __expf(s1-mx);
    float inv = 1.0f/(e0+e1);
    float a0 = e0*inv, a1 = e1*inv;
    int j = t & 63, half = t >> 6;   // half 0..3, each handles 4 nodes
    float bj = blv[j];
    const float* wr = wlds + j*129;
    __syncthreads();
    for(int tile = blockIdx.x; tile < NTILES2; tile += gridDim.x){
        int n0 = tile*NT2;
        __syncthreads();
        {
            const uint4* pe = (const uint4*)((const uint32*)o_em + (size_t)n0*64);
            const uint4* pm = (const uint4*)((const uint32*)o_mm + (size_t)n0*64);
            uint4 ve = pe[t], vm = pm[t];
            float* zd = zlds + t*8;
            zd[0]=a0*blo(ve.x)+a1*blo(vm.x); zd[1]=a0*bhi(ve.x)+a1*bhi(vm.x);
            zd[2]=a0*blo(ve.y)+a1*blo(vm.y); zd[3]=a0*bhi(ve.y)+a1*bhi(vm.y);
            zd[4]=a0*blo(ve.z)+a1*blo(vm.z); zd[5]=a0*bhi(ve.z)+a1*bhi(vm.z);
            zd[6]=a0*blo(ve.w)+a1*blo(vm.w); zd[7]=a0*bhi(ve.w)+a1*bhi(vm.w);
        }
        __syncthreads();
        float acc[4] = {0.f,0.f,0.f,0.f};
        #pragma unroll 1
        for(int kk=0;kk<128;kk+=8){
            float f0=wr[kk],f1=wr[kk+1],f2=wr[kk+2],f3=wr[kk+3];
            float f4=wr[kk+4],f5=wr[kk+5],f6=wr[kk+6],f7=wr[kk+7];
            #pragma unroll
            for(int n=0;n<4;n++){
                const float4* zr = (const float4*)(zlds + (half*4+n)*128 + kk);
                float4 za = zr[0], zb = zr[1];
                acc[n] += za.x*f0 + za.y*f1 + za.z*f2 + za.w*f3
                        + zb.x*f4 + zb.y*f5 + zb.z*f6 + zb.w*f7;
            }
        }
        #pragma unroll
        for(int n=0;n<4;n++)
            out[(size_t)(n0 + half*4 + n)*OUTC + j] = bj + acc[n];
    }
}

extern "C" void kernel_launch(void* const* d_in, const int* in_sizes, int n_in,
                              void* d_out, int out_size, void* d_ws, size_t ws_size,
                              hipStream_t stream)
{
    const float* x_mat    = (const float*)d_in[0];
    const float* x_elem   = (const float*)d_in[1];
    const float* W_pm     = (const float*)d_in[2];
    const float* b_pm     = (const float*)d_in[3];
    const float* W_pe     = (const float*)d_in[4];
    const float* b_pe     = (const float*)d_in[5];
    const float* a_se     = (const float*)d_in[6];
    const float* a_de     = (const float*)d_in[7];
    const float* a_sm     = (const float*)d_in[8];
    const float* a_dm     = (const float*)d_in[9];
    const float* Wk       = (const float*)d_in[10];
    const float* bk       = (const float*)d_in[11];
    const float* qv       = (const float*)d_in[12];
    const float* Wl       = (const float*)d_in[13];
    const float* bl       = (const float*)d_in[14];
    const int* src_em     = (const int*)d_in[15];
    const int* dst_em     = (const int*)d_in[16];
    const int* src_mm     = (const int*)d_in[17];
    const int* dst_mm     = (const int*)d_in[18];
    int nE_em = in_sizes[15];
    int nE_mm = in_sizes[17];

    char* ws = (char*)d_ws;
    size_t off = 0;
    auto alloc = [&](size_t bytes) -> void* {
        void* p = ws + off; off += (bytes + 255) & ~size_t(255); return p;
    };
    ushort16* h_mat   = (ushort16*)alloc((size_t)N_MATN*HIDN*2);
    ushort16* h_elem  = (ushort16*)alloc((size_t)N_ELEMN*HIDN*2);
    float*    asrcEM  = (float*)   alloc((size_t)N_ELEMN*NHEAD*4);
    float*    adstEM  = (float*)   alloc((size_t)N_MATN*NHEAD*4);
    float*    asrcMM  = (float*)   alloc((size_t)N_MATN*NHEAD*4);
    float*    adstMM  = (float*)   alloc((size_t)N_MATN*NHEAD*4);
    int*      offs_em = (int*)     alloc((size_t)(N_MATN+1)*4);
    int*      offs_mm = (int*)     alloc((size_t)(N_MATN+1)*4);
    int*      csr_em  = (int*)     alloc((size_t)1000000*4);
    int*      csr_mm  = (int*)     alloc((size_t)2000000*4);
    ushort16* o_em    = (ushort16*)alloc((size_t)N_MATN*HIDN*2);
    ushort16* o_mm    = (ushort16*)alloc((size_t)N_MATN*HIDN*2);
    int*      bb_em   = (int*)     alloc((size_t)(NBK+1)*4);
    int*      bb_mm   = (int*)     alloc((size_t)(NBK+1)*4);
    int*      bcur_em = (int*)     alloc((size_t)NBK*4);
    int*      bcur_mm = (int*)     alloc((size_t)NBK*4);
    size_t zero_start = off;
    int*      bcnt_em = (int*)     alloc((size_t)NBK*4);
    int*      bcnt_mm = (int*)     alloc((size_t)NBK*4);
    float*    scores  = (float*)   alloc(256);
    size_t zero_bytes = off - zero_start;

    // staged (bucketed) edge buffers alias o_em: dead before agg_both writes o_em.
    // (nE_em + nE_mm) * 4B = 12 MB <= 25.6 MB of o_em.
    uint32* st_em = (uint32*)o_em;
    uint32* st_mm = st_em + nE_em;

    hipMemsetAsync(ws + zero_start, 0, zero_bytes, stream);

    proj_all<<<1024 + N_ELEMN, 256, 0, stream>>>(
        x_elem, W_pe, b_pe, a_se, h_elem, asrcEM,
        x_mat, W_pm, b_pm, a_de, a_sm, a_dm,
        h_mat, adstEM, asrcMM, adstMM);

    bucket_count<<<256, 256, 0, stream>>>(dst_em, nE_em, bcnt_em, dst_mm, nE_mm, bcnt_mm);
    bucket_scan<<<1, 512, 0, stream>>>(bcnt_em, bb_em, bcur_em,
                                       bcnt_mm, bb_mm, bcur_mm,
                                       offs_em, offs_mm, nE_em, nE_mm);

    int nch = (nE_em + BCH - 1)/BCH + (nE_mm + BCH - 1)/BCH;
    bin_pass<<<nch, 256, 0, stream>>>(src_em, dst_em, nE_em, bcur_em, st_em,
                                      src_mm, dst_mm, nE_mm, bcur_mm, st_mm);
    place_pass<<<2*NBK, 256, 0, stream>>>(bb_em, st_em, csr_em, offs_em,
                                          bb_mm, st_mm, csr_mm, offs_mm);

    agg_both<<<4096, 256, 0, stream>>>(offs_em, csr_em, h_elem, asrcEM, adstEM, o_em,
                                       offs_mm, csr_mm, h_mat, asrcMM, adstMM, o_mm);

    score_mfma<<<1024, 256, 0, stream>>>(o_em, o_mm, Wk, bk, qv, scores);
    final_v4<<<2048, 256, 0, stream>>>(o_em, o_mm, Wl, bl, scores, (float*)d_out);
}

// Round 7
// 468.341 us; speedup vs baseline: 1.0173x; 1.0173x over previous
//
#include <hip/hip_runtime.h>
#include <hip/hip_bf16.h>

typedef unsigned int uint32;
typedef unsigned short ushort16;

using bf16x8 = __attribute__((ext_vector_type(8))) short;
using f32x4  = __attribute__((ext_vector_type(4))) float;

#define N_MATN 100000
#define N_ELEMN 118
#define F_MATN 128
#define F_ELEMN 64
#define HIDN 128
#define NHEAD 8
#define OUTC 64
#define NSTRIPS 6250              // 100000 / 16
#define NT2 16
#define NTILES2 (N_MATN/NT2)

#define MATBLK 1024               // mat-projection blocks inside proj_all
#define CNTBLK 128                // bucket-count blocks inside proj_all

// bucketed scatter params
#define SH 8                      // 256 dst nodes per bucket
#define NBK 391                   // ceil(100000/256)
#define BCH 8192                  // edges per bin chunk (368 chunks > 256 CUs)

__device__ __forceinline__ float blo(uint32 u){ return __uint_as_float(u << 16); }
__device__ __forceinline__ float bhi(uint32 u){ return __uint_as_float(u & 0xffff0000u); }
__device__ __forceinline__ ushort16 f2bf(float f){
    uint32 u = __float_as_uint(f);
    uint32 r = u + 0x7FFFu + ((u >> 16) & 1u);   // RNE
    return (ushort16)(r >> 16);
}
__device__ __forceinline__ uint32 pack2(float a, float b){
    return (uint32)f2bf(a) | ((uint32)f2bf(b) << 16);
}
__device__ __forceinline__ bf16x8 cvt8(const float* __restrict__ p){
    bf16x8 r;
    #pragma unroll
    for(int j=0;j<8;j++) r[j] = (short)f2bf(p[j]);
    return r;
}

// ---------------- fused: elem-proj [0,118) | mat-proj [118,1142) | bucket-count [1142,1270)
__global__ __launch_bounds__(256) void proj_all(
    const float* __restrict__ xe, const float* __restrict__ We,
    const float* __restrict__ be, const float* __restrict__ a_se,
    ushort16* __restrict__ h_elem, float* __restrict__ asrc_em,
    const float* __restrict__ x, const float* __restrict__ W,
    const float* __restrict__ bias,
    const float* __restrict__ a_de, const float* __restrict__ a_sm, const float* __restrict__ a_dm,
    ushort16* __restrict__ h,
    float* __restrict__ adst_em, float* __restrict__ asrc_mm, float* __restrict__ adst_mm,
    const int* __restrict__ dst_em, int nE_em, int* __restrict__ bcnt_em,
    const int* __restrict__ dst_mm, int nE_mm, int* __restrict__ bcnt_mm)
{
    int tid = threadIdx.x;
    if(blockIdx.x < N_ELEMN){
        // ---- elem projection (one block per node, 128 active threads)
        __shared__ float xr[F_ELEMN];
        int n = blockIdx.x, c = tid;
        if(c < 16) ((float4*)xr)[c] = ((const float4*)(xe + n*F_ELEMN))[c];
        __syncthreads();
        if(c < 128){
            const float4* Wr = (const float4*)(We + c*F_ELEMN);
            float acc = 0.f;
            #pragma unroll 4
            for(int i=0;i<16;i++){
                float4 w = Wr[i];
                acc += xr[4*i]*w.x + xr[4*i+1]*w.y + xr[4*i+2]*w.z + xr[4*i+3]*w.w;
            }
            acc += be[c];
            h_elem[n*HIDN + c] = f2bf(acc);
            float p = acc * a_se[c];
            #pragma unroll
            for(int m=8;m>=1;m>>=1) p += __shfl_xor(p, m, 16);
            if((c&15)==0) asrc_em[n*NHEAD + (c>>4)] = p;
        }
        return;
    }
    if(blockIdx.x >= N_ELEMN + MATBLK){
        // ---- bucket-count (LDS histograms, int4 streaming)
        __shared__ int he[NBK], hm[NBK];
        for(int i=tid;i<NBK;i+=256){ he[i]=0; hm[i]=0; }
        __syncthreads();
        int cb = blockIdx.x - (N_ELEMN + MATBLK);
        int gt = cb*256 + tid;
        int st = CNTBLK*256;
        {
            int n4 = nE_em >> 2;
            const int4* d4 = (const int4*)dst_em;
            for(int i = gt; i < n4; i += st){
                int4 v = d4[i];
                atomicAdd(&he[v.x>>SH],1); atomicAdd(&he[v.y>>SH],1);
                atomicAdd(&he[v.z>>SH],1); atomicAdd(&he[v.w>>SH],1);
            }
            for(int i = (n4<<2) + gt; i < nE_em; i += st) atomicAdd(&he[dst_em[i]>>SH],1);
        }
        {
            int n4 = nE_mm >> 2;
            const int4* d4 = (const int4*)dst_mm;
            for(int i = gt; i < n4; i += st){
                int4 v = d4[i];
                atomicAdd(&hm[v.x>>SH],1); atomicAdd(&hm[v.y>>SH],1);
                atomicAdd(&hm[v.z>>SH],1); atomicAdd(&hm[v.w>>SH],1);
            }
            for(int i = (n4<<2) + gt; i < nE_mm; i += st) atomicAdd(&hm[dst_mm[i]>>SH],1);
        }
        __syncthreads();
        for(int j=tid;j<NBK;j+=256){
            int a = he[j], b = hm[j];
            if(a) atomicAdd(&bcnt_em[j], a);
            if(b) atomicAdd(&bcnt_mm[j], b);
        }
        return;
    }
    // ---- mat projection (MFMA 16x16x32 bf16)
    int wv = tid >> 6, lane = tid & 63, quad = lane >> 4, sl = lane & 15;
    bf16x8 B[2][4];
    float bc[2], ade[2], asv[2], adv[2];
    #pragma unroll
    for(int i=0;i<2;i++){
        int c = (2*wv+i)*16 + sl;
        const float* wr = W + c*F_MATN;
        #pragma unroll
        for(int ks=0;ks<4;ks++) B[i][ks] = cvt8(wr + ks*32 + quad*8);
        bc[i] = bias[c]; ade[i] = a_de[c]; asv[i] = a_sm[c]; adv[i] = a_dm[c];
    }
    for(int s = blockIdx.x - N_ELEMN; s < NSTRIPS; s += MATBLK){
        int n0 = s*16;
        const float* xrow = x + (size_t)(n0+sl)*F_MATN;
        bf16x8 A[4];
        #pragma unroll
        for(int ks=0;ks<4;ks++) A[ks] = cvt8(xrow + ks*32 + quad*8);
        f32x4 acc[2];
        #pragma unroll
        for(int i=0;i<2;i++){ acc[i][0]=0.f; acc[i][1]=0.f; acc[i][2]=0.f; acc[i][3]=0.f; }
        #pragma unroll
        for(int i=0;i<2;i++)
            #pragma unroll
            for(int ks=0;ks<4;ks++)
                acc[i] = __builtin_amdgcn_mfma_f32_16x16x32_bf16(A[ks], B[i][ks], acc[i], 0, 0, 0);
        #pragma unroll
        for(int i=0;i<2;i++){
            int head = 2*wv + i;
            #pragma unroll
            for(int r=0;r<4;r++){
                float a = acc[i][r] + bc[i];
                int node = n0 + quad*4 + r;
                h[(size_t)node*HIDN + head*16 + sl] = f2bf(a);
                float p0 = a*ade[i], p1 = a*asv[i], p2 = a*adv[i];
                #pragma unroll
                for(int m=8;m>=1;m>>=1){
                    p0 += __shfl_xor(p0, m);
                    p1 += __shfl_xor(p1, m);
                    p2 += __shfl_xor(p2, m);
                }
                if(sl == 0){
                    adst_em[node*NHEAD + head] = p0;
                    asrc_mm[node*NHEAD + head] = p1;
                    adst_mm[node*NHEAD + head] = p2;
                }
            }
        }
    }
}

// ---------------- CSR build stage 2: scan 391 bucket counts (both types), 1 block
__global__ __launch_bounds__(512) void bucket_scan(
    const int* __restrict__ bcnt_em, int* __restrict__ bb_em, int* __restrict__ bcur_em,
    const int* __restrict__ bcnt_mm, int* __restrict__ bb_mm, int* __restrict__ bcur_mm,
    int* __restrict__ offs_em, int* __restrict__ offs_mm, int nE_em, int nE_mm)
{
    __shared__ int wsum[8];
    int t = threadIdx.x, l = t & 63, w = t >> 6;
    // ---- em
    {
        int v = (t < NBK) ? bcnt_em[t] : 0;
        int x = v;
        #pragma unroll
        for(int off=1; off<64; off<<=1){ int y = __shfl_up(x, off); if(l >= off) x += y; }
        if(l == 63) wsum[w] = x;
        __syncthreads();
        int base = 0;
        for(int k=0;k<w;k++) base += wsum[k];
        int excl = base + x - v;
        if(t < NBK){ bb_em[t] = excl; bcur_em[t] = excl; }
        if(t == 0){ bb_em[NBK] = nE_em; offs_em[N_MATN] = nE_em; }
        __syncthreads();
    }
    // ---- mm
    {
        int v = (t < NBK) ? bcnt_mm[t] : 0;
        int x = v;
        #pragma unroll
        for(int off=1; off<64; off<<=1){ int y = __shfl_up(x, off); if(l >= off) x += y; }
        if(l == 63) wsum[w] = x;
        __syncthreads();
        int base = 0;
        for(int k=0;k<w;k++) base += wsum[k];
        int excl = base + x - v;
        if(t < NBK){ bb_mm[t] = excl; bcur_mm[t] = excl; }
        if(t == 0){ bb_mm[NBK] = nE_mm; offs_mm[N_MATN] = nE_mm; }
    }
}

// ---------------- pass A: bin edges into dst-buckets (dense reserved runs, int4 streams)
// staged entry = (dstLow << 17) | src   (src < 2^17, dstLow < 256)
__global__ __launch_bounds__(256) void bin_pass(
    const int* __restrict__ src_em, const int* __restrict__ dst_em, int nE_em,
    int* __restrict__ bcur_em, uint32* __restrict__ st_em,
    const int* __restrict__ src_mm, const int* __restrict__ dst_mm, int nE_mm,
    int* __restrict__ bcur_mm, uint32* __restrict__ st_mm)
{
    __shared__ int cnt[NBK];
    __shared__ int base[NBK];
    int t = threadIdx.x;
    int nch_em = (nE_em + BCH - 1)/BCH;
    int nch_mm = (nE_mm + BCH - 1)/BCH;
    int ntot = nch_em + nch_mm;
    for(int c = blockIdx.x; c < ntot; c += gridDim.x){
        bool em = c < nch_em;
        const int* src = em ? src_em : src_mm;
        const int* dst = em ? dst_em : dst_mm;
        int nE   = em ? nE_em : nE_mm;
        int* bcur = em ? bcur_em : bcur_mm;
        uint32* st = em ? st_em : st_mm;
        int cc = em ? c : c - nch_em;
        int s = cc*BCH;
        int e = s + BCH; if(e > nE) e = nE;
        int len = e - s;
        int n4 = len >> 2;
        const int4* d4 = (const int4*)(dst + s);
        const int4* s4 = (const int4*)(src + s);
        for(int i=t;i<NBK;i+=256) cnt[i] = 0;
        __syncthreads();
        for(int i=t;i<n4;i+=256){
            int4 v = d4[i];
            atomicAdd(&cnt[v.x>>SH],1); atomicAdd(&cnt[v.y>>SH],1);
            atomicAdd(&cnt[v.z>>SH],1); atomicAdd(&cnt[v.w>>SH],1);
        }
        for(int i = s + (n4<<2) + t; i < e; i += 256) atomicAdd(&cnt[dst[i]>>SH], 1);
        __syncthreads();
        for(int i=t;i<NBK;i+=256){
            int v = cnt[i];
            base[i] = v ? atomicAdd(&bcur[i], v) : 0;
            cnt[i] = 0;
        }
        __syncthreads();
        for(int i=t;i<n4;i+=256){
            int4 dv = d4[i];
            int4 sv = s4[i];
            int b, p;
            b = dv.x>>SH; p = base[b] + atomicAdd(&cnt[b],1);
            st[p] = ((uint32)(dv.x & ((1<<SH)-1)) << 17) | (uint32)sv.x;
            b = dv.y>>SH; p = base[b] + atomicAdd(&cnt[b],1);
            st[p] = ((uint32)(dv.y & ((1<<SH)-1)) << 17) | (uint32)sv.y;
            b = dv.z>>SH; p = base[b] + atomicAdd(&cnt[b],1);
            st[p] = ((uint32)(dv.z & ((1<<SH)-1)) << 17) | (uint32)sv.z;
            b = dv.w>>SH; p = base[b] + atomicAdd(&cnt[b],1);
            st[p] = ((uint32)(dv.w & ((1<<SH)-1)) << 17) | (uint32)sv.w;
        }
        for(int i = s + (n4<<2) + t; i < e; i += 256){
            int d = dst[i];
            int b = d >> SH;
            int p = base[b] + atomicAdd(&cnt[b], 1);
            st[p] = ((uint32)(d & ((1<<SH)-1)) << 17) | (uint32)src[i];
        }
        __syncthreads();
    }
}

// ---------------- pass B: per bucket — derive per-dst offsets (writes offs[]) and place
__global__ __launch_bounds__(256) void place_pass(
    const int* __restrict__ bb_em, const uint32* __restrict__ st_em,
    int* __restrict__ csr_em, int* __restrict__ offs_em,
    const int* __restrict__ bb_mm, const uint32* __restrict__ st_mm,
    int* __restrict__ csr_mm, int* __restrict__ offs_mm)
{
    __shared__ int cnt[256];
    __shared__ int wsum[4];
    __shared__ int cur[256];
    int b = blockIdx.x;
    bool em = b < NBK;
    const int* bb        = em ? bb_em : bb_mm;
    const uint32* stp    = em ? st_em : st_mm;
    int* csr             = em ? csr_em : csr_mm;
    int* offs            = em ? offs_em : offs_mm;
    int bk = em ? b : b - NBK;
    int d0 = bk << SH;
    int t = threadIdx.x, l = t & 63, w = t >> 6;
    int nd = N_MATN - d0; if(nd > 256) nd = 256;
    int beg = bb[bk], end = bb[bk+1];
    cnt[t] = 0;
    __syncthreads();
    for(int i = beg + t; i < end; i += 256)
        atomicAdd(&cnt[stp[i] >> 17], 1);
    __syncthreads();
    int v = cnt[t];
    int x = v;
    #pragma unroll
    for(int off=1; off<64; off<<=1){ int y = __shfl_up(x, off); if(l >= off) x += y; }
    if(l == 63) wsum[w] = x;
    __syncthreads();
    int base = beg;
    for(int k=0;k<w;k++) base += wsum[k];
    int excl = base + x - v;
    cur[t] = excl;
    if(t < nd) offs[d0 + t] = excl;
    __syncthreads();
    for(int i = beg + t; i < end; i += 256){
        uint32 vv = stp[i];
        int dl = (int)(vv >> 17);
        int p = atomicAdd(&cur[dl], 1);
        csr[p] = (int)(vv & 0x1FFFFu);
    }
}

// ---------------- aggregation: 16 lanes/edge, 8 edges per wave-iteration (R4 version)
__global__ __launch_bounds__(256) void agg_both(
    const int* __restrict__ offs_em, const int* __restrict__ csr_em,
    const ushort16* __restrict__ h_elem, const float* __restrict__ asrc_em,
    const float* __restrict__ adst_em, ushort16* __restrict__ o_em,
    const int* __restrict__ offs_mm, const int* __restrict__ csr_mm,
    const ushort16* __restrict__ h_mat, const float* __restrict__ asrc_mm,
    const float* __restrict__ adst_mm, ushort16* __restrict__ o_mm)
{
    int lane = threadIdx.x & 63;
    int g = lane >> 4;            // edge slot 0..3
    int q = lane & 15;            // channel quad: channels [q*8, q*8+8)
    int hd = q >> 1;              // head for these channels
    int w = (blockIdx.x*blockDim.x + threadIdx.x) >> 6;
    int nw = (gridDim.x*blockDim.x) >> 6;
    for(int nid = w; nid < 2*N_MATN; nid += nw){
        int nidu = __builtin_amdgcn_readfirstlane(nid);
        bool em = nidu < N_MATN;
        int d = em ? nidu : nidu - N_MATN;
        const int*    offs = em ? offs_em : offs_mm;
        const int*    csr  = em ? csr_em  : csr_mm;
        const uint32* hs   = (const uint32*)(em ? h_elem : h_mat);
        const float*  asp  = em ? asrc_em : asrc_mm;
        const float*  adp  = em ? adst_em : adst_mm;
        uint32*       op   = (uint32*)(em ? o_em : o_mm);
        int beg = offs[d], end = offs[d+1];
        float ad = adp[(unsigned)(d*NHEAD + hd)];
        float denA = 0.f, denB = 0.f;
        float nloA[4] = {0.f,0.f,0.f,0.f}, nhiA[4] = {0.f,0.f,0.f,0.f};
        float nloB[4] = {0.f,0.f,0.f,0.f}, nhiB[4] = {0.f,0.f,0.f,0.f};
        for(int j0 = beg; j0 < end; j0 += 8){
            int e0 = j0 + g, e1 = j0 + 4 + g;
            bool v0 = e0 < end, v1 = e1 < end;
            int s0 = csr[(unsigned)(v0 ? e0 : end - 1)];
            int s1 = csr[(unsigned)(v1 ? e1 : end - 1)];
            // issue all four gathers before any dependent math
            float a0 = asp[(unsigned)(s0*NHEAD + hd)];
            float a1 = asp[(unsigned)(s1*NHEAD + hd)];
            const uint4 h0 = *(const uint4*)(hs + (unsigned)(s0*64 + q*4));
            const uint4 h1 = *(const uint4*)(hs + (unsigned)(s1*64 + q*4));
            float al0 = a0 + ad; al0 = fmaxf(al0, 0.2f*al0);
            float ex0 = __expf(al0); ex0 = v0 ? ex0 : 0.f;
            float al1 = a1 + ad; al1 = fmaxf(al1, 0.2f*al1);
            float ex1 = __expf(al1); ex1 = v1 ? ex1 : 0.f;
            denA += ex0; denB += ex1;
            nloA[0] += blo(h0.x)*ex0; nhiA[0] += bhi(h0.x)*ex0;
            nloA[1] += blo(h0.y)*ex0; nhiA[1] += bhi(h0.y)*ex0;
            nloA[2] += blo(h0.z)*ex0; nhiA[2] += bhi(h0.z)*ex0;
            nloA[3] += blo(h0.w)*ex0; nhiA[3] += bhi(h0.w)*ex0;
            nloB[0] += blo(h1.x)*ex1; nhiB[0] += bhi(h1.x)*ex1;
            nloB[1] += blo(h1.y)*ex1; nhiB[1] += bhi(h1.y)*ex1;
            nloB[2] += blo(h1.z)*ex1; nhiB[2] += bhi(h1.z)*ex1;
            nloB[3] += blo(h1.w)*ex1; nhiB[3] += bhi(h1.w)*ex1;
        }
        float den = denA + denB;
        den += __shfl_xor(den, 16); den += __shfl_xor(den, 32);
        float nlo[4], nhi[4];
        #pragma unroll
        for(int k=0;k<4;k++){
            nlo[k] = nloA[k] + nloB[k];
            nhi[k] = nhiA[k] + nhiB[k];
            nlo[k] += __shfl_xor(nlo[k], 16); nlo[k] += __shfl_xor(nlo[k], 32);
            nhi[k] += __shfl_xor(nhi[k], 16); nhi[k] += __shfl_xor(nhi[k], 32);
        }
        if(g == 0){
            float rdn = 1.0f/(den + 1e-16f);
            uint4 pk;
            pk.x = pack2(fmaxf(nlo[0]*rdn, 0.f), fmaxf(nhi[0]*rdn, 0.f));
            pk.y = pack2(fmaxf(nlo[1]*rdn, 0.f), fmaxf(nhi[1]*rdn, 0.f));
            pk.z = pack2(fmaxf(nlo[2]*rdn, 0.f), fmaxf(nhi[2]*rdn, 0.f));
            pk.w = pack2(fmaxf(nlo[3]*rdn, 0.f), fmaxf(nhi[3]*rdn, 0.f));
            *(uint4*)(op + (size_t)d*64 + q*4) = pk;
        }
    }
}

// ---------------- semantic scores — MFMA; block partials atomically into scores[]
__global__ __launch_bounds__(256) void score_mfma(
    const ushort16* __restrict__ o_em, const ushort16* __restrict__ o_mm,
    const float* __restrict__ Wk, const float* __restrict__ bkv,
    const float* __restrict__ qv, float* __restrict__ scores)
{
    int tid = threadIdx.x;
    int wv = tid >> 6, lane = tid & 63, quad = lane >> 4, sl = lane & 15;
    bf16x8 B[2][4];
    float bkc[2], qc[2];
    #pragma unroll
    for(int i=0;i<2;i++){
        int c = (2*wv+i)*16 + sl;
        const float* wr = Wk + c*HIDN;
        #pragma unroll
        for(int ks=0;ks<4;ks++) B[i][ks] = cvt8(wr + ks*32 + quad*8);
        bkc[i] = bkv[c]; qc[i] = qv[c];
    }
    float se = 0.f, sm = 0.f;
    for(int s = blockIdx.x; s < NSTRIPS; s += gridDim.x){
        int n0 = s*16;
        const bf16x8* rowE = (const bf16x8*)(o_em + (size_t)(n0+sl)*HIDN);
        const bf16x8* rowM = (const bf16x8*)(o_mm + (size_t)(n0+sl)*HIDN);
        bf16x8 AE[4], AM[4];
        #pragma unroll
        for(int ks=0;ks<4;ks++){
            AE[ks] = rowE[ks*4 + quad];
            AM[ks] = rowM[ks*4 + quad];
        }
        f32x4 aE[2], aM[2];
        #pragma unroll
        for(int i=0;i<2;i++){
            aE[i][0]=0.f;aE[i][1]=0.f;aE[i][2]=0.f;aE[i][3]=0.f;
            aM[i][0]=0.f;aM[i][1]=0.f;aM[i][2]=0.f;aM[i][3]=0.f;
        }
        #pragma unroll
        for(int i=0;i<2;i++)
            #pragma unroll
            for(int ks=0;ks<4;ks++){
                aE[i] = __builtin_amdgcn_mfma_f32_16x16x32_bf16(AE[ks], B[i][ks], aE[i], 0, 0, 0);
                aM[i] = __builtin_amdgcn_mfma_f32_16x16x32_bf16(AM[ks], B[i][ks], aM[i], 0, 0, 0);
            }
        #pragma unroll
        for(int i=0;i<2;i++)
            #pragma unroll
            for(int r=0;r<4;r++){
                se += qc[i]*tanhf(aE[i][r] + bkc[i]);
                sm += qc[i]*tanhf(aM[i][r] + bkc[i]);
            }
    }
    #pragma unroll
    for(int m=32;m>=1;m>>=1){ se += __shfl_xor(se,m); sm += __shfl_xor(sm,m); }
    __shared__ float red[8];
    if(lane==0){ red[wv*2]=se; red[wv*2+1]=sm; }
    __syncthreads();
    if(tid==0){
        atomicAdd(&scores[0], red[0]+red[2]+red[4]+red[6]);
        atomicAdd(&scores[1], red[1]+red[3]+red[5]+red[7]);
    }
}

// ---------------- final — LDS-tiled, 4 waves/block, 16 nodes/tile
__global__ __launch_bounds__(256) void final_v4(
    const ushort16* __restrict__ o_em, const ushort16* __restrict__ o_mm,
    const float* __restrict__ Wl, const float* __restrict__ blv,
    const float* __restrict__ scores, float* __restrict__ out)
{
    __shared__ float wlds[64*129];
    __shared__ float zlds[NT2*128];
    int t = threadIdx.x;
    for(int i=t;i<2048;i+=256){
        float4 v = ((const float4*)Wl)[i];
        int r = i >> 5, k4 = i & 31;
        float* d = wlds + r*129 + k4*4;
        d[0]=v.x; d[1]=v.y; d[2]=v.z; d[3]=v.w;
    }
    float s0 = scores[0]*(1.0f/N_MATN), s1 = scores[1]*(1.0f/N_MATN);
    float mx = fmaxf(s0,s1);
    float e0 = __expf(s0-mx), e1 = __expf(s1-mx);
    float inv = 1.0f/(e0+e1);
    float a0 = e0*inv, a1 = e1*inv;
    int j = t & 63, half = t >> 6;   // half 0..3, each handles 4 nodes
    float bj = blv[j];
    const float* wr = wlds + j*129;
    __syncthreads();
    for(int tile = blockIdx.x; tile < NTILES2; tile += gridDim.x){
        int n0 = tile*NT2;
        __syncthreads();
        {
            const uint4* pe = (const uint4*)((const uint32*)o_em + (size_t)n0*64);
            const uint4* pm = (const uint4*)((const uint32*)o_mm + (size_t)n0*64);
            uint4 ve = pe[t], vm = pm[t];
            float* zd = zlds + t*8;
            zd[0]=a0*blo(ve.x)+a1*blo(vm.x); zd[1]=a0*bhi(ve.x)+a1*bhi(vm.x);
            zd[2]=a0*blo(ve.y)+a1*blo(vm.y); zd[3]=a0*bhi(ve.y)+a1*bhi(vm.y);
            zd[4]=a0*blo(ve.z)+a1*blo(vm.z); zd[5]=a0*bhi(ve.z)+a1*bhi(vm.z);
            zd[6]=a0*blo(ve.w)+a1*blo(vm.w); zd[7]=a0*bhi(ve.w)+a1*bhi(vm.w);
        }
        __syncthreads();
        float acc[4] = {0.f,0.f,0.f,0.f};
        #pragma unroll 1
        for(int kk=0;kk<128;kk+=8){
            float f0=wr[kk],f1=wr[kk+1],f2=wr[kk+2],f3=wr[kk+3];
            float f4=wr[kk+4],f5=wr[kk+5],f6=wr[kk+6],f7=wr[kk+7];
            #pragma unroll
            for(int n=0;n<4;n++){
                const float4* zr = (const float4*)(zlds + (half*4+n)*128 + kk);
                float4 za = zr[0], zb = zr[1];
                acc[n] += za.x*f0 + za.y*f1 + za.z*f2 + za.w*f3
                        + zb.x*f4 + zb.y*f5 + zb.z*f6 + zb.w*f7;
            }
        }
        #pragma unroll
        for(int n=0;n<4;n++)
            out[(size_t)(n0 + half*4 + n)*OUTC + j] = bj + acc[n];
    }
}

extern "C" void kernel_launch(void* const* d_in, const int* in_sizes, int n_in,
                              void* d_out, int out_size, void* d_ws, size_t ws_size,
                              hipStream_t stream)
{
    const float* x_mat    = (const float*)d_in[0];
    const float* x_elem   = (const float*)d_in[1];
    const float* W_pm     = (const float*)d_in[2];
    const float* b_pm     = (const float*)d_in[3];
    const float* W_pe     = (const float*)d_in[4];
    const float* b_pe     = (const float*)d_in[5];
    const float* a_se     = (const float*)d_in[6];
    const float* a_de     = (const float*)d_in[7];
    const float* a_sm     = (const float*)d_in[8];
    const float* a_dm     = (const float*)d_in[9];
    const float* Wk       = (const float*)d_in[10];
    const float* bk       = (const float*)d_in[11];
    const float* qv       = (const float*)d_in[12];
    const float* Wl       = (const float*)d_in[13];
    const float* bl       = (const float*)d_in[14];
    const int* src_em     = (const int*)d_in[15];
    const int* dst_em     = (const int*)d_in[16];
    const int* src_mm     = (const int*)d_in[17];
    const int* dst_mm     = (const int*)d_in[18];
    int nE_em = in_sizes[15];
    int nE_mm = in_sizes[17];

    char* ws = (char*)d_ws;
    size_t off = 0;
    auto alloc = [&](size_t bytes) -> void* {
        void* p = ws + off; off += (bytes + 255) & ~size_t(255); return p;
    };
    ushort16* h_mat   = (ushort16*)alloc((size_t)N_MATN*HIDN*2);
    ushort16* h_elem  = (ushort16*)alloc((size_t)N_ELEMN*HIDN*2);
    float*    asrcEM  = (float*)   alloc((size_t)N_ELEMN*NHEAD*4);
    float*    adstEM  = (float*)   alloc((size_t)N_MATN*NHEAD*4);
    float*    asrcMM  = (float*)   alloc((size_t)N_MATN*NHEAD*4);
    float*    adstMM  = (float*)   alloc((size_t)N_MATN*NHEAD*4);
    int*      offs_em = (int*)     alloc((size_t)(N_MATN+1)*4);
    int*      offs_mm = (int*)     alloc((size_t)(N_MATN+1)*4);
    int*      csr_em  = (int*)     alloc((size_t)1000000*4);
    int*      csr_mm  = (int*)     alloc((size_t)2000000*4);
    ushort16* o_em    = (ushort16*)alloc((size_t)N_MATN*HIDN*2);
    ushort16* o_mm    = (ushort16*)alloc((size_t)N_MATN*HIDN*2);
    int*      bb_em   = (int*)     alloc((size_t)(NBK+1)*4);
    int*      bb_mm   = (int*)     alloc((size_t)(NBK+1)*4);
    int*      bcur_em = (int*)     alloc((size_t)NBK*4);
    int*      bcur_mm = (int*)     alloc((size_t)NBK*4);
    size_t zero_start = off;
    int*      bcnt_em = (int*)     alloc((size_t)NBK*4);
    int*      bcnt_mm = (int*)     alloc((size_t)NBK*4);
    float*    scores  = (float*)   alloc(256);
    size_t zero_bytes = off - zero_start;

    // staged (bucketed) edge buffers alias o_em: dead before agg_both writes o_em.
    // (nE_em + nE_mm) * 4B = 12 MB <= 25.6 MB of o_em.
    uint32* st_em = (uint32*)o_em;
    uint32* st_mm = st_em + nE_em;

    hipMemsetAsync(ws + zero_start, 0, zero_bytes, stream);

    proj_all<<<N_ELEMN + MATBLK + CNTBLK, 256, 0, stream>>>(
        x_elem, W_pe, b_pe, a_se, h_elem, asrcEM,
        x_mat, W_pm, b_pm, a_de, a_sm, a_dm,
        h_mat, adstEM, asrcMM, adstMM,
        dst_em, nE_em, bcnt_em, dst_mm, nE_mm, bcnt_mm);

    bucket_scan<<<1, 512, 0, stream>>>(bcnt_em, bb_em, bcur_em,
                                       bcnt_mm, bb_mm, bcur_mm,
                                       offs_em, offs_mm, nE_em, nE_mm);

    int nch = (nE_em + BCH - 1)/BCH + (nE_mm + BCH - 1)/BCH;
    bin_pass<<<nch, 256, 0, stream>>>(src_em, dst_em, nE_em, bcur_em, st_em,
                                      src_mm, dst_mm, nE_mm, bcur_mm, st_mm);
    place_pass<<<2*NBK, 256, 0, stream>>>(bb_em, st_em, csr_em, offs_em,
                                          bb_mm, st_mm, csr_mm, offs_mm);

    agg_both<<<4096, 256, 0, stream>>>(offs_em, csr_em, h_elem, asrcEM, adstEM, o_em,
                                       offs_mm, csr_mm, h_mat, asrcMM, adstMM, o_mm);

    score_mfma<<<1024, 256, 0, stream>>>(o_em, o_mm, Wk, bk, qv, scores);
    final_v4<<<2048, 256, 0, stream>>>(o_em, o_mm, Wl, bl, scores, (float*)d_out);
}

// Round 8
// 448.102 us; speedup vs baseline: 1.0633x; 1.0452x over previous
//
#include <hip/hip_runtime.h>
#include <hip/hip_bf16.h>

typedef unsigned int uint32;
typedef unsigned short ushort16;

using bf16x8 = __attribute__((ext_vector_type(8))) short;
using f32x4  = __attribute__((ext_vector_type(4))) float;

#define N_MATN 100000
#define N_ELEMN 118
#define F_MATN 128
#define F_ELEMN 64
#define HIDN 128
#define NHEAD 8
#define OUTC 64
#define NSTRIPS 6250              // 100000 / 16

#define MATBLK 1024               // mat-projection blocks inside proj_all
#define CNTBLK 128                // bucket-count blocks inside proj_all

// bucketed scatter params
#define SH 8                      // 256 dst nodes per bucket
#define NBK 391                   // ceil(100000/256)
#define BCH 8192                  // edges per bin chunk (368 chunks > 256 CUs)

__device__ __forceinline__ float blo(uint32 u){ return __uint_as_float(u << 16); }
__device__ __forceinline__ float bhi(uint32 u){ return __uint_as_float(u & 0xffff0000u); }
__device__ __forceinline__ ushort16 f2bf(float f){
    uint32 u = __float_as_uint(f);
    uint32 r = u + 0x7FFFu + ((u >> 16) & 1u);   // RNE
    return (ushort16)(r >> 16);
}
__device__ __forceinline__ uint32 pack2(float a, float b){
    return (uint32)f2bf(a) | ((uint32)f2bf(b) << 16);
}
__device__ __forceinline__ bf16x8 cvt8(const float* __restrict__ p){
    bf16x8 r;
    #pragma unroll
    for(int j=0;j<8;j++) r[j] = (short)f2bf(p[j]);
    return r;
}

// ---------------- fused: elem-proj [0,118) | mat-proj [118,1142) | bucket-count [1142,1270)
__global__ __launch_bounds__(256) void proj_all(
    const float* __restrict__ xe, const float* __restrict__ We,
    const float* __restrict__ be, const float* __restrict__ a_se,
    ushort16* __restrict__ h_elem, float* __restrict__ asrc_em,
    const float* __restrict__ x, const float* __restrict__ W,
    const float* __restrict__ bias,
    const float* __restrict__ a_de, const float* __restrict__ a_sm, const float* __restrict__ a_dm,
    ushort16* __restrict__ h,
    float* __restrict__ adst_em, float* __restrict__ asrc_mm, float* __restrict__ adst_mm,
    const int* __restrict__ dst_em, int nE_em, int* __restrict__ bcnt_em,
    const int* __restrict__ dst_mm, int nE_mm, int* __restrict__ bcnt_mm)
{
    int tid = threadIdx.x;
    if(blockIdx.x < N_ELEMN){
        // ---- elem projection (one block per node, 128 active threads)
        __shared__ float xr[F_ELEMN];
        int n = blockIdx.x, c = tid;
        if(c < 16) ((float4*)xr)[c] = ((const float4*)(xe + n*F_ELEMN))[c];
        __syncthreads();
        if(c < 128){
            const float4* Wr = (const float4*)(We + c*F_ELEMN);
            float acc = 0.f;
            #pragma unroll 4
            for(int i=0;i<16;i++){
                float4 w = Wr[i];
                acc += xr[4*i]*w.x + xr[4*i+1]*w.y + xr[4*i+2]*w.z + xr[4*i+3]*w.w;
            }
            acc += be[c];
            h_elem[n*HIDN + c] = f2bf(acc);
            float p = acc * a_se[c];
            #pragma unroll
            for(int m=8;m>=1;m>>=1) p += __shfl_xor(p, m, 16);
            if((c&15)==0) asrc_em[n*NHEAD + (c>>4)] = p;
        }
        return;
    }
    if(blockIdx.x >= N_ELEMN + MATBLK){
        // ---- bucket-count (LDS histograms, int4 streaming)
        __shared__ int he[NBK], hm[NBK];
        for(int i=tid;i<NBK;i+=256){ he[i]=0; hm[i]=0; }
        __syncthreads();
        int cb = blockIdx.x - (N_ELEMN + MATBLK);
        int gt = cb*256 + tid;
        int st = CNTBLK*256;
        {
            int n4 = nE_em >> 2;
            const int4* d4 = (const int4*)dst_em;
            for(int i = gt; i < n4; i += st){
                int4 v = d4[i];
                atomicAdd(&he[v.x>>SH],1); atomicAdd(&he[v.y>>SH],1);
                atomicAdd(&he[v.z>>SH],1); atomicAdd(&he[v.w>>SH],1);
            }
            for(int i = (n4<<2) + gt; i < nE_em; i += st) atomicAdd(&he[dst_em[i]>>SH],1);
        }
        {
            int n4 = nE_mm >> 2;
            const int4* d4 = (const int4*)dst_mm;
            for(int i = gt; i < n4; i += st){
                int4 v = d4[i];
                atomicAdd(&hm[v.x>>SH],1); atomicAdd(&hm[v.y>>SH],1);
                atomicAdd(&hm[v.z>>SH],1); atomicAdd(&hm[v.w>>SH],1);
            }
            for(int i = (n4<<2) + gt; i < nE_mm; i += st) atomicAdd(&hm[dst_mm[i]>>SH],1);
        }
        __syncthreads();
        for(int j=tid;j<NBK;j+=256){
            int a = he[j], b = hm[j];
            if(a) atomicAdd(&bcnt_em[j], a);
            if(b) atomicAdd(&bcnt_mm[j], b);
        }
        return;
    }
    // ---- mat projection (MFMA 16x16x32 bf16)
    int wv = tid >> 6, lane = tid & 63, quad = lane >> 4, sl = lane & 15;
    bf16x8 B[2][4];
    float bc[2], ade[2], asv[2], adv[2];
    #pragma unroll
    for(int i=0;i<2;i++){
        int c = (2*wv+i)*16 + sl;
        const float* wr = W + c*F_MATN;
        #pragma unroll
        for(int ks=0;ks<4;ks++) B[i][ks] = cvt8(wr + ks*32 + quad*8);
        bc[i] = bias[c]; ade[i] = a_de[c]; asv[i] = a_sm[c]; adv[i] = a_dm[c];
    }
    for(int s = blockIdx.x - N_ELEMN; s < NSTRIPS; s += MATBLK){
        int n0 = s*16;
        const float* xrow = x + (size_t)(n0+sl)*F_MATN;
        bf16x8 A[4];
        #pragma unroll
        for(int ks=0;ks<4;ks++) A[ks] = cvt8(xrow + ks*32 + quad*8);
        f32x4 acc[2];
        #pragma unroll
        for(int i=0;i<2;i++){ acc[i][0]=0.f; acc[i][1]=0.f; acc[i][2]=0.f; acc[i][3]=0.f; }
        #pragma unroll
        for(int i=0;i<2;i++)
            #pragma unroll
            for(int ks=0;ks<4;ks++)
                acc[i] = __builtin_amdgcn_mfma_f32_16x16x32_bf16(A[ks], B[i][ks], acc[i], 0, 0, 0);
        #pragma unroll
        for(int i=0;i<2;i++){
            int head = 2*wv + i;
            #pragma unroll
            for(int r=0;r<4;r++){
                float a = acc[i][r] + bc[i];
                int node = n0 + quad*4 + r;
                h[(size_t)node*HIDN + head*16 + sl] = f2bf(a);
                float p0 = a*ade[i], p1 = a*asv[i], p2 = a*adv[i];
                #pragma unroll
                for(int m=8;m>=1;m>>=1){
                    p0 += __shfl_xor(p0, m);
                    p1 += __shfl_xor(p1, m);
                    p2 += __shfl_xor(p2, m);
                }
                if(sl == 0){
                    adst_em[node*NHEAD + head] = p0;
                    asrc_mm[node*NHEAD + head] = p1;
                    adst_mm[node*NHEAD + head] = p2;
                }
            }
        }
    }
}

// ---------------- CSR build stage 2: scan 391 bucket counts (both types), 1 block
__global__ __launch_bounds__(512) void bucket_scan(
    const int* __restrict__ bcnt_em, int* __restrict__ bb_em, int* __restrict__ bcur_em,
    const int* __restrict__ bcnt_mm, int* __restrict__ bb_mm, int* __restrict__ bcur_mm,
    int* __restrict__ offs_em, int* __restrict__ offs_mm, int nE_em, int nE_mm)
{
    __shared__ int wsum[8];
    int t = threadIdx.x, l = t & 63, w = t >> 6;
    // ---- em
    {
        int v = (t < NBK) ? bcnt_em[t] : 0;
        int x = v;
        #pragma unroll
        for(int off=1; off<64; off<<=1){ int y = __shfl_up(x, off); if(l >= off) x += y; }
        if(l == 63) wsum[w] = x;
        __syncthreads();
        int base = 0;
        for(int k=0;k<w;k++) base += wsum[k];
        int excl = base + x - v;
        if(t < NBK){ bb_em[t] = excl; bcur_em[t] = excl; }
        if(t == 0){ bb_em[NBK] = nE_em; offs_em[N_MATN] = nE_em; }
        __syncthreads();
    }
    // ---- mm
    {
        int v = (t < NBK) ? bcnt_mm[t] : 0;
        int x = v;
        #pragma unroll
        for(int off=1; off<64; off<<=1){ int y = __shfl_up(x, off); if(l >= off) x += y; }
        if(l == 63) wsum[w] = x;
        __syncthreads();
        int base = 0;
        for(int k=0;k<w;k++) base += wsum[k];
        int excl = base + x - v;
        if(t < NBK){ bb_mm[t] = excl; bcur_mm[t] = excl; }
        if(t == 0){ bb_mm[NBK] = nE_mm; offs_mm[N_MATN] = nE_mm; }
    }
}

// ---------------- pass A: bin edges into dst-buckets (dense reserved runs, int4 streams)
// staged entry = (dstLow << 17) | src   (src < 2^17, dstLow < 256)
__global__ __launch_bounds__(256) void bin_pass(
    const int* __restrict__ src_em, const int* __restrict__ dst_em, int nE_em,
    int* __restrict__ bcur_em, uint32* __restrict__ st_em,
    const int* __restrict__ src_mm, const int* __restrict__ dst_mm, int nE_mm,
    int* __restrict__ bcur_mm, uint32* __restrict__ st_mm)
{
    __shared__ int cnt[NBK];
    __shared__ int base[NBK];
    int t = threadIdx.x;
    int nch_em = (nE_em + BCH - 1)/BCH;
    int nch_mm = (nE_mm + BCH - 1)/BCH;
    int ntot = nch_em + nch_mm;
    for(int c = blockIdx.x; c < ntot; c += gridDim.x){
        bool em = c < nch_em;
        const int* src = em ? src_em : src_mm;
        const int* dst = em ? dst_em : dst_mm;
        int nE   = em ? nE_em : nE_mm;
        int* bcur = em ? bcur_em : bcur_mm;
        uint32* st = em ? st_em : st_mm;
        int cc = em ? c : c - nch_em;
        int s = cc*BCH;
        int e = s + BCH; if(e > nE) e = nE;
        int len = e - s;
        int n4 = len >> 2;
        const int4* d4 = (const int4*)(dst + s);
        const int4* s4 = (const int4*)(src + s);
        for(int i=t;i<NBK;i+=256) cnt[i] = 0;
        __syncthreads();
        for(int i=t;i<n4;i+=256){
            int4 v = d4[i];
            atomicAdd(&cnt[v.x>>SH],1); atomicAdd(&cnt[v.y>>SH],1);
            atomicAdd(&cnt[v.z>>SH],1); atomicAdd(&cnt[v.w>>SH],1);
        }
        for(int i = s + (n4<<2) + t; i < e; i += 256) atomicAdd(&cnt[dst[i]>>SH], 1);
        __syncthreads();
        for(int i=t;i<NBK;i+=256){
            int v = cnt[i];
            base[i] = v ? atomicAdd(&bcur[i], v) : 0;
            cnt[i] = 0;
        }
        __syncthreads();
        for(int i=t;i<n4;i+=256){
            int4 dv = d4[i];
            int4 sv = s4[i];
            int b, p;
            b = dv.x>>SH; p = base[b] + atomicAdd(&cnt[b],1);
            st[p] = ((uint32)(dv.x & ((1<<SH)-1)) << 17) | (uint32)sv.x;
            b = dv.y>>SH; p = base[b] + atomicAdd(&cnt[b],1);
            st[p] = ((uint32)(dv.y & ((1<<SH)-1)) << 17) | (uint32)sv.y;
            b = dv.z>>SH; p = base[b] + atomicAdd(&cnt[b],1);
            st[p] = ((uint32)(dv.z & ((1<<SH)-1)) << 17) | (uint32)sv.z;
            b = dv.w>>SH; p = base[b] + atomicAdd(&cnt[b],1);
            st[p] = ((uint32)(dv.w & ((1<<SH)-1)) << 17) | (uint32)sv.w;
        }
        for(int i = s + (n4<<2) + t; i < e; i += 256){
            int d = dst[i];
            int b = d >> SH;
            int p = base[b] + atomicAdd(&cnt[b], 1);
            st[p] = ((uint32)(d & ((1<<SH)-1)) << 17) | (uint32)src[i];
        }
        __syncthreads();
    }
}

// ---------------- pass B: per bucket — derive per-dst offsets (writes offs[]) and place
__global__ __launch_bounds__(256) void place_pass(
    const int* __restrict__ bb_em, const uint32* __restrict__ st_em,
    int* __restrict__ csr_em, int* __restrict__ offs_em,
    const int* __restrict__ bb_mm, const uint32* __restrict__ st_mm,
    int* __restrict__ csr_mm, int* __restrict__ offs_mm)
{
    __shared__ int cnt[256];
    __shared__ int wsum[4];
    __shared__ int cur[256];
    int b = blockIdx.x;
    bool em = b < NBK;
    const int* bb        = em ? bb_em : bb_mm;
    const uint32* stp    = em ? st_em : st_mm;
    int* csr             = em ? csr_em : csr_mm;
    int* offs            = em ? offs_em : offs_mm;
    int bk = em ? b : b - NBK;
    int d0 = bk << SH;
    int t = threadIdx.x, l = t & 63, w = t >> 6;
    int nd = N_MATN - d0; if(nd > 256) nd = 256;
    int beg = bb[bk], end = bb[bk+1];
    cnt[t] = 0;
    __syncthreads();
    for(int i = beg + t; i < end; i += 256)
        atomicAdd(&cnt[stp[i] >> 17], 1);
    __syncthreads();
    int v = cnt[t];
    int x = v;
    #pragma unroll
    for(int off=1; off<64; off<<=1){ int y = __shfl_up(x, off); if(l >= off) x += y; }
    if(l == 63) wsum[w] = x;
    __syncthreads();
    int base = beg;
    for(int k=0;k<w;k++) base += wsum[k];
    int excl = base + x - v;
    cur[t] = excl;
    if(t < nd) offs[d0 + t] = excl;
    __syncthreads();
    for(int i = beg + t; i < end; i += 256){
        uint32 vv = stp[i];
        int dl = (int)(vv >> 17);
        int p = atomicAdd(&cur[dl], 1);
        csr[p] = (int)(vv & 0x1FFFFu);
    }
}

// ---------------- aggregation: 16 lanes/edge, 8 edges per wave-iteration (R4 version)
__global__ __launch_bounds__(256) void agg_both(
    const int* __restrict__ offs_em, const int* __restrict__ csr_em,
    const ushort16* __restrict__ h_elem, const float* __restrict__ asrc_em,
    const float* __restrict__ adst_em, ushort16* __restrict__ o_em,
    const int* __restrict__ offs_mm, const int* __restrict__ csr_mm,
    const ushort16* __restrict__ h_mat, const float* __restrict__ asrc_mm,
    const float* __restrict__ adst_mm, ushort16* __restrict__ o_mm)
{
    int lane = threadIdx.x & 63;
    int g = lane >> 4;            // edge slot 0..3
    int q = lane & 15;            // channel quad: channels [q*8, q*8+8)
    int hd = q >> 1;              // head for these channels
    int w = (blockIdx.x*blockDim.x + threadIdx.x) >> 6;
    int nw = (gridDim.x*blockDim.x) >> 6;
    for(int nid = w; nid < 2*N_MATN; nid += nw){
        int nidu = __builtin_amdgcn_readfirstlane(nid);
        bool em = nidu < N_MATN;
        int d = em ? nidu : nidu - N_MATN;
        const int*    offs = em ? offs_em : offs_mm;
        const int*    csr  = em ? csr_em  : csr_mm;
        const uint32* hs   = (const uint32*)(em ? h_elem : h_mat);
        const float*  asp  = em ? asrc_em : asrc_mm;
        const float*  adp  = em ? adst_em : adst_mm;
        uint32*       op   = (uint32*)(em ? o_em : o_mm);
        int beg = offs[d], end = offs[d+1];
        float ad = adp[(unsigned)(d*NHEAD + hd)];
        float denA = 0.f, denB = 0.f;
        float nloA[4] = {0.f,0.f,0.f,0.f}, nhiA[4] = {0.f,0.f,0.f,0.f};
        float nloB[4] = {0.f,0.f,0.f,0.f}, nhiB[4] = {0.f,0.f,0.f,0.f};
        for(int j0 = beg; j0 < end; j0 += 8){
            int e0 = j0 + g, e1 = j0 + 4 + g;
            bool v0 = e0 < end, v1 = e1 < end;
            int s0 = csr[(unsigned)(v0 ? e0 : end - 1)];
            int s1 = csr[(unsigned)(v1 ? e1 : end - 1)];
            // issue all four gathers before any dependent math
            float a0 = asp[(unsigned)(s0*NHEAD + hd)];
            float a1 = asp[(unsigned)(s1*NHEAD + hd)];
            const uint4 h0 = *(const uint4*)(hs + (unsigned)(s0*64 + q*4));
            const uint4 h1 = *(const uint4*)(hs + (unsigned)(s1*64 + q*4));
            float al0 = a0 + ad; al0 = fmaxf(al0, 0.2f*al0);
            float ex0 = __expf(al0); ex0 = v0 ? ex0 : 0.f;
            float al1 = a1 + ad; al1 = fmaxf(al1, 0.2f*al1);
            float ex1 = __expf(al1); ex1 = v1 ? ex1 : 0.f;
            denA += ex0; denB += ex1;
            nloA[0] += blo(h0.x)*ex0; nhiA[0] += bhi(h0.x)*ex0;
            nloA[1] += blo(h0.y)*ex0; nhiA[1] += bhi(h0.y)*ex0;
            nloA[2] += blo(h0.z)*ex0; nhiA[2] += bhi(h0.z)*ex0;
            nloA[3] += blo(h0.w)*ex0; nhiA[3] += bhi(h0.w)*ex0;
            nloB[0] += blo(h1.x)*ex1; nhiB[0] += bhi(h1.x)*ex1;
            nloB[1] += blo(h1.y)*ex1; nhiB[1] += bhi(h1.y)*ex1;
            nloB[2] += blo(h1.z)*ex1; nhiB[2] += bhi(h1.z)*ex1;
            nloB[3] += blo(h1.w)*ex1; nhiB[3] += bhi(h1.w)*ex1;
        }
        float den = denA + denB;
        den += __shfl_xor(den, 16); den += __shfl_xor(den, 32);
        float nlo[4], nhi[4];
        #pragma unroll
        for(int k=0;k<4;k++){
            nlo[k] = nloA[k] + nloB[k];
            nhi[k] = nhiA[k] + nhiB[k];
            nlo[k] += __shfl_xor(nlo[k], 16); nlo[k] += __shfl_xor(nlo[k], 32);
            nhi[k] += __shfl_xor(nhi[k], 16); nhi[k] += __shfl_xor(nhi[k], 32);
        }
        if(g == 0){
            float rdn = 1.0f/(den + 1e-16f);
            uint4 pk;
            pk.x = pack2(fmaxf(nlo[0]*rdn, 0.f), fmaxf(nhi[0]*rdn, 0.f));
            pk.y = pack2(fmaxf(nlo[1]*rdn, 0.f), fmaxf(nhi[1]*rdn, 0.f));
            pk.z = pack2(fmaxf(nlo[2]*rdn, 0.f), fmaxf(nhi[2]*rdn, 0.f));
            pk.w = pack2(fmaxf(nlo[3]*rdn, 0.f), fmaxf(nhi[3]*rdn, 0.f));
            *(uint4*)(op + (size_t)d*64 + q*4) = pk;
        }
    }
}

// ---------------- semantic scores — MFMA; block partials atomically into scores[]
__global__ __launch_bounds__(256) void score_mfma(
    const ushort16* __restrict__ o_em, const ushort16* __restrict__ o_mm,
    const float* __restrict__ Wk, const float* __restrict__ bkv,
    const float* __restrict__ qv, float* __restrict__ scores)
{
    int tid = threadIdx.x;
    int wv = tid >> 6, lane = tid & 63, quad = lane >> 4, sl = lane & 15;
    bf16x8 B[2][4];
    float bkc[2], qc[2];
    #pragma unroll
    for(int i=0;i<2;i++){
        int c = (2*wv+i)*16 + sl;
        const float* wr = Wk + c*HIDN;
        #pragma unroll
        for(int ks=0;ks<4;ks++) B[i][ks] = cvt8(wr + ks*32 + quad*8);
        bkc[i] = bkv[c]; qc[i] = qv[c];
    }
    float se = 0.f, sm = 0.f;
    for(int s = blockIdx.x; s < NSTRIPS; s += gridDim.x){
        int n0 = s*16;
        const bf16x8* rowE = (const bf16x8*)(o_em + (size_t)(n0+sl)*HIDN);
        const bf16x8* rowM = (const bf16x8*)(o_mm + (size_t)(n0+sl)*HIDN);
        bf16x8 AE[4], AM[4];
        #pragma unroll
        for(int ks=0;ks<4;ks++){
            AE[ks] = rowE[ks*4 + quad];
            AM[ks] = rowM[ks*4 + quad];
        }
        f32x4 aE[2], aM[2];
        #pragma unroll
        for(int i=0;i<2;i++){
            aE[i][0]=0.f;aE[i][1]=0.f;aE[i][2]=0.f;aE[i][3]=0.f;
            aM[i][0]=0.f;aM[i][1]=0.f;aM[i][2]=0.f;aM[i][3]=0.f;
        }
        #pragma unroll
        for(int i=0;i<2;i++)
            #pragma unroll
            for(int ks=0;ks<4;ks++){
                aE[i] = __builtin_amdgcn_mfma_f32_16x16x32_bf16(AE[ks], B[i][ks], aE[i], 0, 0, 0);
                aM[i] = __builtin_amdgcn_mfma_f32_16x16x32_bf16(AM[ks], B[i][ks], aM[i], 0, 0, 0);
            }
        #pragma unroll
        for(int i=0;i<2;i++)
            #pragma unroll
            for(int r=0;r<4;r++){
                se += qc[i]*tanhf(aE[i][r] + bkc[i]);
                sm += qc[i]*tanhf(aM[i][r] + bkc[i]);
            }
    }
    #pragma unroll
    for(int m=32;m>=1;m>>=1){ se += __shfl_xor(se,m); sm += __shfl_xor(sm,m); }
    __shared__ float red[8];
    if(lane==0){ red[wv*2]=se; red[wv*2+1]=sm; }
    __syncthreads();
    if(tid==0){
        atomicAdd(&scores[0], red[0]+red[2]+red[4]+red[6]);
        atomicAdd(&scores[1], red[1]+red[3]+red[5]+red[7]);
    }
}

// ---------------- final — MFMA GEMM: out = (a0*o_em + a1*o_mm) @ Wl^T + bl, no LDS
__global__ __launch_bounds__(256) void final_mfma(
    const ushort16* __restrict__ o_em, const ushort16* __restrict__ o_mm,
    const float* __restrict__ Wl, const float* __restrict__ blv,
    const float* __restrict__ scores, float* __restrict__ out)
{
    int tid = threadIdx.x;
    int lane = tid & 63, quad = lane >> 4, sl = lane & 15;
    // B fragments: 4 col-groups (64 cols) x 4 k-slices; layout identical to proj_mat
    bf16x8 B[4][4];
    float blc[4];
    #pragma unroll
    for(int i=0;i<4;i++){
        int c = i*16 + sl;
        const float* wr = Wl + c*HIDN;
        #pragma unroll
        for(int ks=0;ks<4;ks++) B[i][ks] = cvt8(wr + ks*32 + quad*8);
        blc[i] = blv[c];
    }
    float s0 = scores[0]*(1.0f/N_MATN), s1 = scores[1]*(1.0f/N_MATN);
    float mx = fmaxf(s0,s1);
    float e0 = __expf(s0-mx), e1 = __expf(s1-mx);
    float inv = 1.0f/(e0+e1);
    float a0 = e0*inv, a1 = e1*inv;
    int gw = (blockIdx.x*blockDim.x + tid) >> 6;
    int nwv = (gridDim.x*blockDim.x) >> 6;
    for(int s = gw; s < NSTRIPS; s += nwv){
        int n0 = s*16;
        const uint4* rowE = (const uint4*)((const uint32*)o_em + (size_t)(n0+sl)*64);
        const uint4* rowM = (const uint4*)((const uint32*)o_mm + (size_t)(n0+sl)*64);
        bf16x8 A[4];
        #pragma unroll
        for(int ks=0;ks<4;ks++){
            uint4 e = rowE[ks*4 + quad];   // channels ks*32+quad*8 .. +8
            uint4 m = rowM[ks*4 + quad];
            bf16x8 a;
            a[0] = (short)f2bf(a0*blo(e.x)+a1*blo(m.x));
            a[1] = (short)f2bf(a0*bhi(e.x)+a1*bhi(m.x));
            a[2] = (short)f2bf(a0*blo(e.y)+a1*blo(m.y));
            a[3] = (short)f2bf(a0*bhi(e.y)+a1*bhi(m.y));
            a[4] = (short)f2bf(a0*blo(e.z)+a1*blo(m.z));
            a[5] = (short)f2bf(a0*bhi(e.z)+a1*bhi(m.z));
            a[6] = (short)f2bf(a0*blo(e.w)+a1*blo(m.w));
            a[7] = (short)f2bf(a0*bhi(e.w)+a1*bhi(m.w));
            A[ks] = a;
        }
        f32x4 acc[4];
        #pragma unroll
        for(int i=0;i<4;i++){ acc[i][0]=0.f; acc[i][1]=0.f; acc[i][2]=0.f; acc[i][3]=0.f; }
        #pragma unroll
        for(int i=0;i<4;i++)
            #pragma unroll
            for(int ks=0;ks<4;ks++)
                acc[i] = __builtin_amdgcn_mfma_f32_16x16x32_bf16(A[ks], B[i][ks], acc[i], 0, 0, 0);
        #pragma unroll
        for(int i=0;i<4;i++)
            #pragma unroll
            for(int r=0;r<4;r++)
                out[(size_t)(n0 + quad*4 + r)*OUTC + i*16 + sl] = acc[i][r] + blc[i];
    }
}

extern "C" void kernel_launch(void* const* d_in, const int* in_sizes, int n_in,
                              void* d_out, int out_size, void* d_ws, size_t ws_size,
                              hipStream_t stream)
{
    const float* x_mat    = (const float*)d_in[0];
    const float* x_elem   = (const float*)d_in[1];
    const float* W_pm     = (const float*)d_in[2];
    const float* b_pm     = (const float*)d_in[3];
    const float* W_pe     = (const float*)d_in[4];
    const float* b_pe     = (const float*)d_in[5];
    const float* a_se     = (const float*)d_in[6];
    const float* a_de     = (const float*)d_in[7];
    const float* a_sm     = (const float*)d_in[8];
    const float* a_dm     = (const float*)d_in[9];
    const float* Wk       = (const float*)d_in[10];
    const float* bk       = (const float*)d_in[11];
    const float* qv       = (const float*)d_in[12];
    const float* Wl       = (const float*)d_in[13];
    const float* bl       = (const float*)d_in[14];
    const int* src_em     = (const int*)d_in[15];
    const int* dst_em     = (const int*)d_in[16];
    const int* src_mm     = (const int*)d_in[17];
    const int* dst_mm     = (const int*)d_in[18];
    int nE_em = in_sizes[15];
    int nE_mm = in_sizes[17];

    char* ws = (char*)d_ws;
    size_t off = 0;
    auto alloc = [&](size_t bytes) -> void* {
        void* p = ws + off; off += (bytes + 255) & ~size_t(255); return p;
    };
    ushort16* h_mat   = (ushort16*)alloc((size_t)N_MATN*HIDN*2);
    ushort16* h_elem  = (ushort16*)alloc((size_t)N_ELEMN*HIDN*2);
    float*    asrcEM  = (float*)   alloc((size_t)N_ELEMN*NHEAD*4);
    float*    adstEM  = (float*)   alloc((size_t)N_MATN*NHEAD*4);
    float*    asrcMM  = (float*)   alloc((size_t)N_MATN*NHEAD*4);
    float*    adstMM  = (float*)   alloc((size_t)N_MATN*NHEAD*4);
    int*      offs_em = (int*)     alloc((size_t)(N_MATN+1)*4);
    int*      offs_mm = (int*)     alloc((size_t)(N_MATN+1)*4);
    int*      csr_em  = (int*)     alloc((size_t)1000000*4);
    int*      csr_mm  = (int*)     alloc((size_t)2000000*4);
    ushort16* o_em    = (ushort16*)alloc((size_t)N_MATN*HIDN*2);
    ushort16* o_mm    = (ushort16*)alloc((size_t)N_MATN*HIDN*2);
    int*      bb_em   = (int*)     alloc((size_t)(NBK+1)*4);
    int*      bb_mm   = (int*)     alloc((size_t)(NBK+1)*4);
    int*      bcur_em = (int*)     alloc((size_t)NBK*4);
    int*      bcur_mm = (int*)     alloc((size_t)NBK*4);
    size_t zero_start = off;
    int*      bcnt_em = (int*)     alloc((size_t)NBK*4);
    int*      bcnt_mm = (int*)     alloc((size_t)NBK*4);
    float*    scores  = (float*)   alloc(256);
    size_t zero_bytes = off - zero_start;

    // staged (bucketed) edge buffers alias o_em: dead before agg_both writes o_em.
    // (nE_em + nE_mm) * 4B = 12 MB <= 25.6 MB of o_em.
    uint32* st_em = (uint32*)o_em;
    uint32* st_mm = st_em + nE_em;

    hipMemsetAsync(ws + zero_start, 0, zero_bytes, stream);

    proj_all<<<N_ELEMN + MATBLK + CNTBLK, 256, 0, stream>>>(
        x_elem, W_pe, b_pe, a_se, h_elem, asrcEM,
        x_mat, W_pm, b_pm, a_de, a_sm, a_dm,
        h_mat, adstEM, asrcMM, adstMM,
        dst_em, nE_em, bcnt_em, dst_mm, nE_mm, bcnt_mm);

    bucket_scan<<<1, 512, 0, stream>>>(bcnt_em, bb_em, bcur_em,
                                       bcnt_mm, bb_mm, bcur_mm,
                                       offs_em, offs_mm, nE_em, nE_mm);

    int nch = (nE_em + BCH - 1)/BCH + (nE_mm + BCH - 1)/BCH;
    bin_pass<<<nch, 256, 0, stream>>>(src_em, dst_em, nE_em, bcur_em, st_em,
                                      src_mm, dst_mm, nE_mm, bcur_mm, st_mm);
    place_pass<<<2*NBK, 256, 0, stream>>>(bb_em, st_em, csr_em, offs_em,
                                          bb_mm, st_mm, csr_mm, offs_mm);

    agg_both<<<4096, 256, 0, stream>>>(offs_em, csr_em, h_elem, asrcEM, adstEM, o_em,
                                       offs_mm, csr_mm, h_mat, asrcMM, adstMM, o_mm);

    score_mfma<<<1024, 256, 0, stream>>>(o_em, o_mm, Wk, bk, qv, scores);
    final_mfma<<<1563, 256, 0, stream>>>(o_em, o_mm, Wl, bl, scores, (float*)d_out);
}

// Round 9
// 421.170 us; speedup vs baseline: 1.1313x; 1.0639x over previous
//
#include <hip/hip_runtime.h>
#include <hip/hip_bf16.h>

typedef unsigned int uint32;
typedef unsigned short ushort16;

using bf16x8 = __attribute__((ext_vector_type(8))) short;
using f32x4  = __attribute__((ext_vector_type(4))) float;

#define N_MATN 100000
#define N_ELEMN 118
#define F_MATN 128
#define F_ELEMN 64
#define HIDN 128
#define NHEAD 8
#define OUTC 64
#define NSTRIPS 6250              // 100000 / 16

#define MATBLK 1024               // mat-projection blocks inside proj_all
#define CNTBLK 128                // bucket-count blocks inside proj_all

// bucketed scatter params
#define SH 8                      // 256 dst nodes per bucket
#define NBK 391                   // ceil(100000/256)
#define BCH 8192                  // edges per bin chunk (368 chunks > 256 CUs)
#define LOCN 6144                 // place_pass LDS CSR segment capacity

__device__ __forceinline__ float blo(uint32 u){ return __uint_as_float(u << 16); }
__device__ __forceinline__ float bhi(uint32 u){ return __uint_as_float(u & 0xffff0000u); }
__device__ __forceinline__ ushort16 f2bf(float f){
    uint32 u = __float_as_uint(f);
    uint32 r = u + 0x7FFFu + ((u >> 16) & 1u);   // RNE
    return (ushort16)(r >> 16);
}
__device__ __forceinline__ uint32 pack2(float a, float b){
    return (uint32)f2bf(a) | ((uint32)f2bf(b) << 16);
}
__device__ __forceinline__ bf16x8 cvt8(const float* __restrict__ p){
    bf16x8 r;
    #pragma unroll
    for(int j=0;j<8;j++) r[j] = (short)f2bf(p[j]);
    return r;
}

// ---------------- fused: elem-proj [0,118) | mat-proj [118,1142) | bucket-count [1142,1270)
__global__ __launch_bounds__(256) void proj_all(
    const float* __restrict__ xe, const float* __restrict__ We,
    const float* __restrict__ be, const float* __restrict__ a_se,
    ushort16* __restrict__ h_elem, float* __restrict__ asrc_em,
    const float* __restrict__ x, const float* __restrict__ W,
    const float* __restrict__ bias,
    const float* __restrict__ a_de, const float* __restrict__ a_sm, const float* __restrict__ a_dm,
    ushort16* __restrict__ h,
    float* __restrict__ adst_em, float* __restrict__ asrc_mm, float* __restrict__ adst_mm,
    const int* __restrict__ dst_em, int nE_em, int* __restrict__ bcnt_em,
    const int* __restrict__ dst_mm, int nE_mm, int* __restrict__ bcnt_mm)
{
    int tid = threadIdx.x;
    if(blockIdx.x < N_ELEMN){
        // ---- elem projection (one block per node, 128 active threads)
        __shared__ float xr[F_ELEMN];
        int n = blockIdx.x, c = tid;
        if(c < 16) ((float4*)xr)[c] = ((const float4*)(xe + n*F_ELEMN))[c];
        __syncthreads();
        if(c < 128){
            const float4* Wr = (const float4*)(We + c*F_ELEMN);
            float acc = 0.f;
            #pragma unroll 4
            for(int i=0;i<16;i++){
                float4 w = Wr[i];
                acc += xr[4*i]*w.x + xr[4*i+1]*w.y + xr[4*i+2]*w.z + xr[4*i+3]*w.w;
            }
            acc += be[c];
            h_elem[n*HIDN + c] = f2bf(acc);
            float p = acc * a_se[c];
            #pragma unroll
            for(int m=8;m>=1;m>>=1) p += __shfl_xor(p, m, 16);
            if((c&15)==0) asrc_em[n*NHEAD + (c>>4)] = p;
        }
        return;
    }
    if(blockIdx.x >= N_ELEMN + MATBLK){
        // ---- bucket-count (LDS histograms, int4 streaming)
        __shared__ int he[NBK], hm[NBK];
        for(int i=tid;i<NBK;i+=256){ he[i]=0; hm[i]=0; }
        __syncthreads();
        int cb = blockIdx.x - (N_ELEMN + MATBLK);
        int gt = cb*256 + tid;
        int st = CNTBLK*256;
        {
            int n4 = nE_em >> 2;
            const int4* d4 = (const int4*)dst_em;
            for(int i = gt; i < n4; i += st){
                int4 v = d4[i];
                atomicAdd(&he[v.x>>SH],1); atomicAdd(&he[v.y>>SH],1);
                atomicAdd(&he[v.z>>SH],1); atomicAdd(&he[v.w>>SH],1);
            }
            for(int i = (n4<<2) + gt; i < nE_em; i += st) atomicAdd(&he[dst_em[i]>>SH],1);
        }
        {
            int n4 = nE_mm >> 2;
            const int4* d4 = (const int4*)dst_mm;
            for(int i = gt; i < n4; i += st){
                int4 v = d4[i];
                atomicAdd(&hm[v.x>>SH],1); atomicAdd(&hm[v.y>>SH],1);
                atomicAdd(&hm[v.z>>SH],1); atomicAdd(&hm[v.w>>SH],1);
            }
            for(int i = (n4<<2) + gt; i < nE_mm; i += st) atomicAdd(&hm[dst_mm[i]>>SH],1);
        }
        __syncthreads();
        for(int j=tid;j<NBK;j+=256){
            int a = he[j], b = hm[j];
            if(a) atomicAdd(&bcnt_em[j], a);
            if(b) atomicAdd(&bcnt_mm[j], b);
        }
        return;
    }
    // ---- mat projection (MFMA 16x16x32 bf16)
    int wv = tid >> 6, lane = tid & 63, quad = lane >> 4, sl = lane & 15;
    bf16x8 B[2][4];
    float bc[2], ade[2], asv[2], adv[2];
    #pragma unroll
    for(int i=0;i<2;i++){
        int c = (2*wv+i)*16 + sl;
        const float* wr = W + c*F_MATN;
        #pragma unroll
        for(int ks=0;ks<4;ks++) B[i][ks] = cvt8(wr + ks*32 + quad*8);
        bc[i] = bias[c]; ade[i] = a_de[c]; asv[i] = a_sm[c]; adv[i] = a_dm[c];
    }
    for(int s = blockIdx.x - N_ELEMN; s < NSTRIPS; s += MATBLK){
        int n0 = s*16;
        const float* xrow = x + (size_t)(n0+sl)*F_MATN;
        bf16x8 A[4];
        #pragma unroll
        for(int ks=0;ks<4;ks++) A[ks] = cvt8(xrow + ks*32 + quad*8);
        f32x4 acc[2];
        #pragma unroll
        for(int i=0;i<2;i++){ acc[i][0]=0.f; acc[i][1]=0.f; acc[i][2]=0.f; acc[i][3]=0.f; }
        #pragma unroll
        for(int i=0;i<2;i++)
            #pragma unroll
            for(int ks=0;ks<4;ks++)
                acc[i] = __builtin_amdgcn_mfma_f32_16x16x32_bf16(A[ks], B[i][ks], acc[i], 0, 0, 0);
        #pragma unroll
        for(int i=0;i<2;i++){
            int head = 2*wv + i;
            #pragma unroll
            for(int r=0;r<4;r++){
                float a = acc[i][r] + bc[i];
                int node = n0 + quad*4 + r;
                h[(size_t)node*HIDN + head*16 + sl] = f2bf(a);
                float p0 = a*ade[i], p1 = a*asv[i], p2 = a*adv[i];
                #pragma unroll
                for(int m=8;m>=1;m>>=1){
                    p0 += __shfl_xor(p0, m);
                    p1 += __shfl_xor(p1, m);
                    p2 += __shfl_xor(p2, m);
                }
                if(sl == 0){
                    adst_em[node*NHEAD + head] = p0;
                    asrc_mm[node*NHEAD + head] = p1;
                    adst_mm[node*NHEAD + head] = p2;
                }
            }
        }
    }
}

// ---------------- CSR build stage 2: scan 391 bucket counts (both types), 1 block
__global__ __launch_bounds__(512) void bucket_scan(
    const int* __restrict__ bcnt_em, int* __restrict__ bb_em, int* __restrict__ bcur_em,
    const int* __restrict__ bcnt_mm, int* __restrict__ bb_mm, int* __restrict__ bcur_mm,
    int* __restrict__ offs_em, int* __restrict__ offs_mm, int nE_em, int nE_mm)
{
    __shared__ int wsum[8];
    int t = threadIdx.x, l = t & 63, w = t >> 6;
    // ---- em
    {
        int v = (t < NBK) ? bcnt_em[t] : 0;
        int x = v;
        #pragma unroll
        for(int off=1; off<64; off<<=1){ int y = __shfl_up(x, off); if(l >= off) x += y; }
        if(l == 63) wsum[w] = x;
        __syncthreads();
        int base = 0;
        for(int k=0;k<w;k++) base += wsum[k];
        int excl = base + x - v;
        if(t < NBK){ bb_em[t] = excl; bcur_em[t] = excl; }
        if(t == 0){ bb_em[NBK] = nE_em; offs_em[N_MATN] = nE_em; }
        __syncthreads();
    }
    // ---- mm
    {
        int v = (t < NBK) ? bcnt_mm[t] : 0;
        int x = v;
        #pragma unroll
        for(int off=1; off<64; off<<=1){ int y = __shfl_up(x, off); if(l >= off) x += y; }
        if(l == 63) wsum[w] = x;
        __syncthreads();
        int base = 0;
        for(int k=0;k<w;k++) base += wsum[k];
        int excl = base + x - v;
        if(t < NBK){ bb_mm[t] = excl; bcur_mm[t] = excl; }
        if(t == 0){ bb_mm[NBK] = nE_mm; offs_mm[N_MATN] = nE_mm; }
    }
}

// ---------------- pass A: bin edges into dst-buckets; LDS-staged, coalesced writeout
// staged entry = (dstLow << 17) | src   (src < 2^17, dstLow < 256)
__global__ __launch_bounds__(256) void bin_pass(
    const int* __restrict__ src_em, const int* __restrict__ dst_em, int nE_em,
    int* __restrict__ bcur_em, uint32* __restrict__ st_em,
    const int* __restrict__ src_mm, const int* __restrict__ dst_mm, int nE_mm,
    int* __restrict__ bcur_mm, uint32* __restrict__ st_mm)
{
    __shared__ int cnt[NBK];
    __shared__ int lexcl[NBK];
    __shared__ int gbase[NBK];
    __shared__ int wsumA[4];
    __shared__ int wsumB[4];
    __shared__ uint32 stg[BCH];
    __shared__ unsigned short bid[BCH];
    int t = threadIdx.x, l = t & 63, w = t >> 6;
    int nch_em = (nE_em + BCH - 1)/BCH;
    int nch_mm = (nE_mm + BCH - 1)/BCH;
    int ntot = nch_em + nch_mm;
    for(int i=t;i<NBK;i+=256) cnt[i] = 0;
    for(int c = blockIdx.x; c < ntot; c += gridDim.x){
        bool em = c < nch_em;
        const int* src = em ? src_em : src_mm;
        const int* dst = em ? dst_em : dst_mm;
        int nE   = em ? nE_em : nE_mm;
        int* bcur = em ? bcur_em : bcur_mm;
        uint32* st = em ? st_em : st_mm;
        int cc = em ? c : c - nch_em;
        int s = cc*BCH;
        int e = s + BCH; if(e > nE) e = nE;
        int len = e - s;
        int n4 = len >> 2;
        const int4* d4 = (const int4*)(dst + s);
        const int4* s4 = (const int4*)(src + s);
        __syncthreads();                       // cnt zeroed (init or prev iter)
        // histogram
        for(int i=t;i<n4;i+=256){
            int4 v = d4[i];
            atomicAdd(&cnt[v.x>>SH],1); atomicAdd(&cnt[v.y>>SH],1);
            atomicAdd(&cnt[v.z>>SH],1); atomicAdd(&cnt[v.w>>SH],1);
        }
        for(int i = s + (n4<<2) + t; i < e; i += 256) atomicAdd(&cnt[dst[i]>>SH], 1);
        __syncthreads();
        // scan 391 entries (two 256-wide segments), reserve global runs, zero cnt
        {
            int vA = cnt[t];
            int xA = vA;
            #pragma unroll
            for(int off=1; off<64; off<<=1){ int y = __shfl_up(xA, off); if(l >= off) xA += y; }
            if(l == 63) wsumA[w] = xA;
            __syncthreads();
            int baseA = 0;
            for(int k=0;k<w;k++) baseA += wsumA[k];
            int exA = baseA + xA - vA;
            int totA = wsumA[0]+wsumA[1]+wsumA[2]+wsumA[3];
            int idxB = 256 + t;
            int vB = (idxB < NBK) ? cnt[idxB] : 0;
            int xB = vB;
            #pragma unroll
            for(int off=1; off<64; off<<=1){ int y = __shfl_up(xB, off); if(l >= off) xB += y; }
            if(l == 63) wsumB[w] = xB;
            __syncthreads();
            int baseB = 0;
            for(int k=0;k<w;k++) baseB += wsumB[k];
            int exB = totA + baseB + xB - vB;
            lexcl[t] = exA;
            gbase[t] = atomicAdd(&bcur[t], vA);
            cnt[t] = 0;
            if(idxB < NBK){
                lexcl[idxB] = exB;
                gbase[idxB] = atomicAdd(&bcur[idxB], vB);
                cnt[idxB] = 0;
            }
        }
        __syncthreads();
        // replay into LDS staging (ordered by bucket)
        for(int i=t;i<n4;i+=256){
            int4 dv = d4[i];
            int4 sv = s4[i];
            int b, p;
            b = dv.x>>SH; p = lexcl[b] + atomicAdd(&cnt[b],1);
            stg[p] = ((uint32)(dv.x & ((1<<SH)-1)) << 17) | (uint32)sv.x; bid[p] = (unsigned short)b;
            b = dv.y>>SH; p = lexcl[b] + atomicAdd(&cnt[b],1);
            stg[p] = ((uint32)(dv.y & ((1<<SH)-1)) << 17) | (uint32)sv.y; bid[p] = (unsigned short)b;
            b = dv.z>>SH; p = lexcl[b] + atomicAdd(&cnt[b],1);
            stg[p] = ((uint32)(dv.z & ((1<<SH)-1)) << 17) | (uint32)sv.z; bid[p] = (unsigned short)b;
            b = dv.w>>SH; p = lexcl[b] + atomicAdd(&cnt[b],1);
            stg[p] = ((uint32)(dv.w & ((1<<SH)-1)) << 17) | (uint32)sv.w; bid[p] = (unsigned short)b;
        }
        for(int i = s + (n4<<2) + t; i < e; i += 256){
            int d = dst[i];
            int b = d >> SH;
            int p = lexcl[b] + atomicAdd(&cnt[b], 1);
            stg[p] = ((uint32)(d & ((1<<SH)-1)) << 17) | (uint32)src[i]; bid[p] = (unsigned short)b;
        }
        __syncthreads();
        // coalesced writeout: consecutive i -> same bucket run -> consecutive global addr
        for(int i=t;i<len;i+=256){
            int b = bid[i];
            st[gbase[b] + (i - lexcl[b])] = stg[i];
        }
        // cnt already zeroed in scan epilogue... it was used as replay cursor; re-zero
        __syncthreads();
        for(int i=t;i<NBK;i+=256) cnt[i] = 0;
    }
}

// ---------------- pass B: per bucket — offsets + LDS-ordered CSR segment, coalesced out
__global__ __launch_bounds__(256) void place_pass(
    const int* __restrict__ bb_em, const uint32* __restrict__ st_em,
    int* __restrict__ csr_em, int* __restrict__ offs_em,
    const int* __restrict__ bb_mm, const uint32* __restrict__ st_mm,
    int* __restrict__ csr_mm, int* __restrict__ offs_mm)
{
    __shared__ int cnt[256];
    __shared__ int wsum[4];
    __shared__ int cur[256];
    __shared__ uint32 loc[LOCN];
    int b = blockIdx.x;
    bool em = b < NBK;
    const int* bb        = em ? bb_em : bb_mm;
    const uint32* stp    = em ? st_em : st_mm;
    int* csr             = em ? csr_em : csr_mm;
    int* offs            = em ? offs_em : offs_mm;
    int bk = em ? b : b - NBK;
    int d0 = bk << SH;
    int t = threadIdx.x, l = t & 63, w = t >> 6;
    int nd = N_MATN - d0; if(nd > 256) nd = 256;
    int beg = bb[bk], end = bb[bk+1];
    int len = end - beg;
    cnt[t] = 0;
    __syncthreads();
    for(int i = beg + t; i < end; i += 256)
        atomicAdd(&cnt[stp[i] >> 17], 1);
    __syncthreads();
    int v = cnt[t];
    int x = v;
    #pragma unroll
    for(int off=1; off<64; off<<=1){ int y = __shfl_up(x, off); if(l >= off) x += y; }
    if(l == 63) wsum[w] = x;
    __syncthreads();
    int base = 0;
    for(int k=0;k<w;k++) base += wsum[k];
    int excl = base + x - v;            // local (0-based) exclusive prefix
    if(t < nd) offs[d0 + t] = beg + excl;
    if(len <= LOCN){
        cur[t] = excl;
        __syncthreads();
        for(int i = beg + t; i < end; i += 256){
            uint32 vv = stp[i];
            int dl = (int)(vv >> 17);
            int p = atomicAdd(&cur[dl], 1);
            loc[p] = vv & 0x1FFFFu;
        }
        __syncthreads();
        for(int i = t; i < len; i += 256)
            csr[beg + i] = (int)loc[i];
    } else {
        cur[t] = beg + excl;
        __syncthreads();
        for(int i = beg + t; i < end; i += 256){
            uint32 vv = stp[i];
            int dl = (int)(vv >> 17);
            int p = atomicAdd(&cur[dl], 1);
            csr[p] = (int)(vv & 0x1FFFFu);
        }
    }
}

// ---------------- aggregation: 16 lanes/edge, 8 edges per wave-iteration (R4 version)
__global__ __launch_bounds__(256) void agg_both(
    const int* __restrict__ offs_em, const int* __restrict__ csr_em,
    const ushort16* __restrict__ h_elem, const float* __restrict__ asrc_em,
    const float* __restrict__ adst_em, ushort16* __restrict__ o_em,
    const int* __restrict__ offs_mm, const int* __restrict__ csr_mm,
    const ushort16* __restrict__ h_mat, const float* __restrict__ asrc_mm,
    const float* __restrict__ adst_mm, ushort16* __restrict__ o_mm)
{
    int lane = threadIdx.x & 63;
    int g = lane >> 4;            // edge slot 0..3
    int q = lane & 15;            // channel quad: channels [q*8, q*8+8)
    int hd = q >> 1;              // head for these channels
    int w = (blockIdx.x*blockDim.x + threadIdx.x) >> 6;
    int nw = (gridDim.x*blockDim.x) >> 6;
    for(int nid = w; nid < 2*N_MATN; nid += nw){
        int nidu = __builtin_amdgcn_readfirstlane(nid);
        bool em = nidu < N_MATN;
        int d = em ? nidu : nidu - N_MATN;
        const int*    offs = em ? offs_em : offs_mm;
        const int*    csr  = em ? csr_em  : csr_mm;
        const uint32* hs   = (const uint32*)(em ? h_elem : h_mat);
        const float*  asp  = em ? asrc_em : asrc_mm;
        const float*  adp  = em ? adst_em : adst_mm;
        uint32*       op   = (uint32*)(em ? o_em : o_mm);
        int beg = offs[d], end = offs[d+1];
        float ad = adp[(unsigned)(d*NHEAD + hd)];
        float denA = 0.f, denB = 0.f;
        float nloA[4] = {0.f,0.f,0.f,0.f}, nhiA[4] = {0.f,0.f,0.f,0.f};
        float nloB[4] = {0.f,0.f,0.f,0.f}, nhiB[4] = {0.f,0.f,0.f,0.f};
        for(int j0 = beg; j0 < end; j0 += 8){
            int e0 = j0 + g, e1 = j0 + 4 + g;
            bool v0 = e0 < end, v1 = e1 < end;
            int s0 = csr[(unsigned)(v0 ? e0 : end - 1)];
            int s1 = csr[(unsigned)(v1 ? e1 : end - 1)];
            // issue all four gathers before any dependent math
            float a0 = asp[(unsigned)(s0*NHEAD + hd)];
            float a1 = asp[(unsigned)(s1*NHEAD + hd)];
            const uint4 h0 = *(const uint4*)(hs + (unsigned)(s0*64 + q*4));
            const uint4 h1 = *(const uint4*)(hs + (unsigned)(s1*64 + q*4));
            float al0 = a0 + ad; al0 = fmaxf(al0, 0.2f*al0);
            float ex0 = __expf(al0); ex0 = v0 ? ex0 : 0.f;
            float al1 = a1 + ad; al1 = fmaxf(al1, 0.2f*al1);
            float ex1 = __expf(al1); ex1 = v1 ? ex1 : 0.f;
            denA += ex0; denB += ex1;
            nloA[0] += blo(h0.x)*ex0; nhiA[0] += bhi(h0.x)*ex0;
            nloA[1] += blo(h0.y)*ex0; nhiA[1] += bhi(h0.y)*ex0;
            nloA[2] += blo(h0.z)*ex0; nhiA[2] += bhi(h0.z)*ex0;
            nloA[3] += blo(h0.w)*ex0; nhiA[3] += bhi(h0.w)*ex0;
            nloB[0] += blo(h1.x)*ex1; nhiB[0] += bhi(h1.x)*ex1;
            nloB[1] += blo(h1.y)*ex1; nhiB[1] += bhi(h1.y)*ex1;
            nloB[2] += blo(h1.z)*ex1; nhiB[2] += bhi(h1.z)*ex1;
            nloB[3] += blo(h1.w)*ex1; nhiB[3] += bhi(h1.w)*ex1;
        }
        float den = denA + denB;
        den += __shfl_xor(den, 16); den += __shfl_xor(den, 32);
        float nlo[4], nhi[4];
        #pragma unroll
        for(int k=0;k<4;k++){
            nlo[k] = nloA[k] + nloB[k];
            nhi[k] = nhiA[k] + nhiB[k];
            nlo[k] += __shfl_xor(nlo[k], 16); nlo[k] += __shfl_xor(nlo[k], 32);
            nhi[k] += __shfl_xor(nhi[k], 16); nhi[k] += __shfl_xor(nhi[k], 32);
        }
        if(g == 0){
            float rdn = 1.0f/(den + 1e-16f);
            uint4 pk;
            pk.x = pack2(fmaxf(nlo[0]*rdn, 0.f), fmaxf(nhi[0]*rdn, 0.f));
            pk.y = pack2(fmaxf(nlo[1]*rdn, 0.f), fmaxf(nhi[1]*rdn, 0.f));
            pk.z = pack2(fmaxf(nlo[2]*rdn, 0.f), fmaxf(nhi[2]*rdn, 0.f));
            pk.w = pack2(fmaxf(nlo[3]*rdn, 0.f), fmaxf(nhi[3]*rdn, 0.f));
            *(uint4*)(op + (size_t)d*64 + q*4) = pk;
        }
    }
}

// ---------------- semantic scores — MFMA; block partials atomically into scores[]
__global__ __launch_bounds__(256) void score_mfma(
    const ushort16* __restrict__ o_em, const ushort16* __restrict__ o_mm,
    const float* __restrict__ Wk, const float* __restrict__ bkv,
    const float* __restrict__ qv, float* __restrict__ scores)
{
    int tid = threadIdx.x;
    int wv = tid >> 6, lane = tid & 63, quad = lane >> 4, sl = lane & 15;
    bf16x8 B[2][4];
    float bkc[2], qc[2];
    #pragma unroll
    for(int i=0;i<2;i++){
        int c = (2*wv+i)*16 + sl;
        const float* wr = Wk + c*HIDN;
        #pragma unroll
        for(int ks=0;ks<4;ks++) B[i][ks] = cvt8(wr + ks*32 + quad*8);
        bkc[i] = bkv[c]; qc[i] = qv[c];
    }
    float se = 0.f, sm = 0.f;
    for(int s = blockIdx.x; s < NSTRIPS; s += gridDim.x){
        int n0 = s*16;
        const bf16x8* rowE = (const bf16x8*)(o_em + (size_t)(n0+sl)*HIDN);
        const bf16x8* rowM = (const bf16x8*)(o_mm + (size_t)(n0+sl)*HIDN);
        bf16x8 AE[4], AM[4];
        #pragma unroll
        for(int ks=0;ks<4;ks++){
            AE[ks] = rowE[ks*4 + quad];
            AM[ks] = rowM[ks*4 + quad];
        }
        f32x4 aE[2], aM[2];
        #pragma unroll
        for(int i=0;i<2;i++){
            aE[i][0]=0.f;aE[i][1]=0.f;aE[i][2]=0.f;aE[i][3]=0.f;
            aM[i][0]=0.f;aM[i][1]=0.f;aM[i][2]=0.f;aM[i][3]=0.f;
        }
        #pragma unroll
        for(int i=0;i<2;i++)
            #pragma unroll
            for(int ks=0;ks<4;ks++){
                aE[i] = __builtin_amdgcn_mfma_f32_16x16x32_bf16(AE[ks], B[i][ks], aE[i], 0, 0, 0);
                aM[i] = __builtin_amdgcn_mfma_f32_16x16x32_bf16(AM[ks], B[i][ks], aM[i], 0, 0, 0);
            }
        #pragma unroll
        for(int i=0;i<2;i++)
            #pragma unroll
            for(int r=0;r<4;r++){
                se += qc[i]*tanhf(aE[i][r] + bkc[i]);
                sm += qc[i]*tanhf(aM[i][r] + bkc[i]);
            }
    }
    #pragma unroll
    for(int m=32;m>=1;m>>=1){ se += __shfl_xor(se,m); sm += __shfl_xor(sm,m); }
    __shared__ float red[8];
    if(lane==0){ red[wv*2]=se; red[wv*2+1]=sm; }
    __syncthreads();
    if(tid==0){
        atomicAdd(&scores[0], red[0]+red[2]+red[4]+red[6]);
        atomicAdd(&scores[1], red[1]+red[3]+red[5]+red[7]);
    }
}

// ---------------- final — MFMA GEMM: out = (a0*o_em + a1*o_mm) @ Wl^T + bl, no LDS
__global__ __launch_bounds__(256) void final_mfma(
    const ushort16* __restrict__ o_em, const ushort16* __restrict__ o_mm,
    const float* __restrict__ Wl, const float* __restrict__ blv,
    const float* __restrict__ scores, float* __restrict__ out)
{
    int tid = threadIdx.x;
    int lane = tid & 63, quad = lane >> 4, sl = lane & 15;
    // B fragments: 4 col-groups (64 cols) x 4 k-slices; layout identical to proj_mat
    bf16x8 B[4][4];
    float blc[4];
    #pragma unroll
    for(int i=0;i<4;i++){
        int c = i*16 + sl;
        const float* wr = Wl + c*HIDN;
        #pragma unroll
        for(int ks=0;ks<4;ks++) B[i][ks] = cvt8(wr + ks*32 + quad*8);
        blc[i] = blv[c];
    }
    float s0 = scores[0]*(1.0f/N_MATN), s1 = scores[1]*(1.0f/N_MATN);
    float mx = fmaxf(s0,s1);
    float e0 = __expf(s0-mx), e1 = __expf(s1-mx);
    float inv = 1.0f/(e0+e1);
    float a0 = e0*inv, a1 = e1*inv;
    int gw = (blockIdx.x*blockDim.x + tid) >> 6;
    int nwv = (gridDim.x*blockDim.x) >> 6;
    for(int s = gw; s < NSTRIPS; s += nwv){
        int n0 = s*16;
        const uint4* rowE = (const uint4*)((const uint32*)o_em + (size_t)(n0+sl)*64);
        const uint4* rowM = (const uint4*)((const uint32*)o_mm + (size_t)(n0+sl)*64);
        bf16x8 A[4];
        #pragma unroll
        for(int ks=0;ks<4;ks++){
            uint4 e = rowE[ks*4 + quad];   // channels ks*32+quad*8 .. +8
            uint4 m = rowM[ks*4 + quad];
            bf16x8 a;
            a[0] = (short)f2bf(a0*blo(e.x)+a1*blo(m.x));
            a[1] = (short)f2bf(a0*bhi(e.x)+a1*bhi(m.x));
            a[2] = (short)f2bf(a0*blo(e.y)+a1*blo(m.y));
            a[3] = (short)f2bf(a0*bhi(e.y)+a1*bhi(m.y));
            a[4] = (short)f2bf(a0*blo(e.z)+a1*blo(m.z));
            a[5] = (short)f2bf(a0*bhi(e.z)+a1*bhi(m.z));
            a[6] = (short)f2bf(a0*blo(e.w)+a1*blo(m.w));
            a[7] = (short)f2bf(a0*bhi(e.w)+a1*bhi(m.w));
            A[ks] = a;
        }
        f32x4 acc[4];
        #pragma unroll
        for(int i=0;i<4;i++){ acc[i][0]=0.f; acc[i][1]=0.f; acc[i][2]=0.f; acc[i][3]=0.f; }
        #pragma unroll
        for(int i=0;i<4;i++)
            #pragma unroll
            for(int ks=0;ks<4;ks++)
                acc[i] = __builtin_amdgcn_mfma_f32_16x16x32_bf16(A[ks], B[i][ks], acc[i], 0, 0, 0);
        #pragma unroll
        for(int i=0;i<4;i++)
            #pragma unroll
            for(int r=0;r<4;r++)
                out[(size_t)(n0 + quad*4 + r)*OUTC + i*16 + sl] = acc[i][r] + blc[i];
    }
}

extern "C" void kernel_launch(void* const* d_in, const int* in_sizes, int n_in,
                              void* d_out, int out_size, void* d_ws, size_t ws_size,
                              hipStream_t stream)
{
    const float* x_mat    = (const float*)d_in[0];
    const float* x_elem   = (const float*)d_in[1];
    const float* W_pm     = (const float*)d_in[2];
    const float* b_pm     = (const float*)d_in[3];
    const float* W_pe     = (const float*)d_in[4];
    const float* b_pe     = (const float*)d_in[5];
    const float* a_se     = (const float*)d_in[6];
    const float* a_de     = (const float*)d_in[7];
    const float* a_sm     = (const float*)d_in[8];
    const float* a_dm     = (const float*)d_in[9];
    const float* Wk       = (const float*)d_in[10];
    const float* bk       = (const float*)d_in[11];
    const float* qv       = (const float*)d_in[12];
    const float* Wl       = (const float*)d_in[13];
    const float* bl       = (const float*)d_in[14];
    const int* src_em     = (const int*)d_in[15];
    const int* dst_em     = (const int*)d_in[16];
    const int* src_mm     = (const int*)d_in[17];
    const int* dst_mm     = (const int*)d_in[18];
    int nE_em = in_sizes[15];
    int nE_mm = in_sizes[17];

    char* ws = (char*)d_ws;
    size_t off = 0;
    auto alloc = [&](size_t bytes) -> void* {
        void* p = ws + off; off += (bytes + 255) & ~size_t(255); return p;
    };
    ushort16* h_mat   = (ushort16*)alloc((size_t)N_MATN*HIDN*2);
    ushort16* h_elem  = (ushort16*)alloc((size_t)N_ELEMN*HIDN*2);
    float*    asrcEM  = (float*)   alloc((size_t)N_ELEMN*NHEAD*4);
    float*    adstEM  = (float*)   alloc((size_t)N_MATN*NHEAD*4);
    float*    asrcMM  = (float*)   alloc((size_t)N_MATN*NHEAD*4);
    float*    adstMM  = (float*)   alloc((size_t)N_MATN*NHEAD*4);
    int*      offs_em = (int*)     alloc((size_t)(N_MATN+1)*4);
    int*      offs_mm = (int*)     alloc((size_t)(N_MATN+1)*4);
    int*      csr_em  = (int*)     alloc((size_t)1000000*4);
    int*      csr_mm  = (int*)     alloc((size_t)2000000*4);
    ushort16* o_em    = (ushort16*)alloc((size_t)N_MATN*HIDN*2);
    ushort16* o_mm    = (ushort16*)alloc((size_t)N_MATN*HIDN*2);
    int*      bb_em   = (int*)     alloc((size_t)(NBK+1)*4);
    int*      bb_mm   = (int*)     alloc((size_t)(NBK+1)*4);
    int*      bcur_em = (int*)     alloc((size_t)NBK*4);
    int*      bcur_mm = (int*)     alloc((size_t)NBK*4);
    size_t zero_start = off;
    int*      bcnt_em = (int*)     alloc((size_t)NBK*4);
    int*      bcnt_mm = (int*)     alloc((size_t)NBK*4);
    float*    scores  = (float*)   alloc(256);
    size_t zero_bytes = off - zero_start;

    // staged (bucketed) edge buffers alias o_em: dead before agg_both writes o_em.
    // (nE_em + nE_mm) * 4B = 12 MB <= 25.6 MB of o_em.
    uint32* st_em = (uint32*)o_em;
    uint32* st_mm = st_em + nE_em;

    hipMemsetAsync(ws + zero_start, 0, zero_bytes, stream);

    proj_all<<<N_ELEMN + MATBLK + CNTBLK, 256, 0, stream>>>(
        x_elem, W_pe, b_pe, a_se, h_elem, asrcEM,
        x_mat, W_pm, b_pm, a_de, a_sm, a_dm,
        h_mat, adstEM, asrcMM, adstMM,
        dst_em, nE_em, bcnt_em, dst_mm, nE_mm, bcnt_mm);

    bucket_scan<<<1, 512, 0, stream>>>(bcnt_em, bb_em, bcur_em,
                                       bcnt_mm, bb_mm, bcur_mm,
                                       offs_em, offs_mm, nE_em, nE_mm);

    int nch = (nE_em + BCH - 1)/BCH + (nE_mm + BCH - 1)/BCH;
    bin_pass<<<nch, 256, 0, stream>>>(src_em, dst_em, nE_em, bcur_em, st_em,
                                      src_mm, dst_mm, nE_mm, bcur_mm, st_mm);
    place_pass<<<2*NBK, 256, 0, stream>>>(bb_em, st_em, csr_em, offs_em,
                                          bb_mm, st_mm, csr_mm, offs_mm);

    agg_both<<<4096, 256, 0, stream>>>(offs_em, csr_em, h_elem, asrcEM, adstEM, o_em,
                                       offs_mm, csr_mm, h_mat, asrcMM, adstMM, o_mm);

    score_mfma<<<1024, 256, 0, stream>>>(o_em, o_mm, Wk, bk, qv, scores);
    final_mfma<<<1563, 256, 0, stream>>>(o_em, o_mm, Wl, bl, scores, (float*)d_out);
}